// Round 6
// baseline (1535.011 us; speedup 1.0000x reference)
//
#include <hip/hip_runtime.h>
#include <math.h>

#define DI static __device__ __forceinline__

typedef __attribute__((ext_vector_type(8))) short bhalf8;
typedef __attribute__((ext_vector_type(4))) float floatx4;

// ---------- bf16 helpers ----------
DI unsigned short f2bf(float f){
  union { float f; unsigned u; } v; v.f = f;
  unsigned r = (v.u + 0x7fffu + ((v.u >> 16) & 1u)) >> 16;
  return (unsigned short)r;
}
DI float bflo(unsigned v){ return __uint_as_float(v << 16); }
DI float bfhi(unsigned v){ return __uint_as_float(v & 0xffff0000u); }
DI unsigned pk2(float a, float b){ return (unsigned)f2bf(a) | ((unsigned)f2bf(b) << 16); }
DI void unpack8(uint4 u, float* a){
  a[0]=bflo(u.x); a[1]=bfhi(u.x); a[2]=bflo(u.y); a[3]=bfhi(u.y);
  a[4]=bflo(u.z); a[5]=bfhi(u.z); a[6]=bflo(u.w); a[7]=bfhi(u.w);
}
DI float fc(float4 v, int j){ return j==0 ? v.x : (j==1 ? v.y : (j==2 ? v.z : v.w)); }
// tanh-form GELU: max |err| vs exact ~3e-4
DI float gelu(float x){
  float u = x*(0.7978845608f + 0.0356774081f*x*x);
  float e = __expf(2.f*u);
  return x - x/(e + 1.f);
}

// ---------- prep kernels ----------
__global__ void k_scale_vec(const float* __restrict__ src, float* __restrict__ dst, int n, float s){
  int i = blockIdx.x*256 + threadIdx.x;
  if (i < n) dst[i] = src[i]*s;
}
// pack weight (O x K f32 row-major) into bf16 MFMA B-fragment order
__global__ void k_fragw(const float* __restrict__ src, unsigned short* __restrict__ dst,
                        int n, int K, float scale){
  int t = blockIdx.x*256 + threadIdx.x;
  if (t >= n) return;
  int j = t & 7, lane = (t >> 3) & 63, rest = t >> 9;
  int KS = K >> 5;
  int ks = rest % KS, nt = rest / KS;
  int row = nt*16 + (lane & 15);
  int col = ks*32 + ((lane >> 4) << 3) + j;
  dst[t] = f2bf(src[(size_t)row*K + col] * scale);
}
// relative-position bias in C-fragment layout: biasf[((h*4+mt)*4+nt)*256 + lane*4 + r]
__global__ void k_bias(const float* __restrict__ rpb, float* __restrict__ biasf){
  int t = blockIdx.x*256 + threadIdx.x;   // 32768 total
  int r = t & 3, lane = (t>>2) & 63, nt = (t>>8) & 3, mt = (t>>10) & 3, h = t>>12;
  int qtok = mt*16 + (lane>>4)*4 + r;
  int ktok = nt*16 + (lane & 15);
  int idx = ((qtok>>3) - (ktok>>3) + 7)*15 + ((qtok&7) - (ktok&7) + 7);
  biasf[t] = rpb[idx*8 + h];
}

// ---------- kernel 1: MFMA convs + LN1 + QKV MFMA GEMMs (unchanged) ----------
__global__ __launch_bounds__(256) void k_front(
    const float* __restrict__ LH, const float* __restrict__ HL,
    const float* __restrict__ HH, const float* __restrict__ Sp,
    const unsigned short* __restrict__ wxf, const float* __restrict__ bx,
    const unsigned short* __restrict__ wzf, const float* __restrict__ bz,
    const unsigned short* __restrict__ wyf, const float* __restrict__ by,
    const float* __restrict__ g1x, const float* __restrict__ b1x,
    const float* __restrict__ g1y, const float* __restrict__ b1y,
    const unsigned short* __restrict__ wqf, const float* __restrict__ bq,
    const unsigned short* __restrict__ wkf, const float* __restrict__ bk,
    const unsigned short* __restrict__ wvf, const float* __restrict__ bv,
    unsigned short* __restrict__ z0, unsigned short* __restrict__ qg,
    unsigned short* __restrict__ kg, unsigned short* __restrict__ vtg)
{
  __shared__ __align__(16) unsigned short astg[64*72];    // 9216B conv-A staging (one 64ch plane)
  __shared__ __align__(16) unsigned short sbufA[64*288];  // xn [64][264] / staging / vt [256][72]
  __shared__ __align__(16) unsigned short sbufB[64*264];  // yn [64][264]
  // LN scratch lives in sbufA tail bytes [33792, 36352): rows only use up to 16887 ushorts
  float* part  = (float*)(sbufA + 16896);   // [256][2]
  float* stats = part + 512;                // [64][2]

  const int tid = threadIdx.x;
  const int lane = tid & 63, wave = tid >> 6, col = lane & 15, quad = lane >> 4;
  const int mB = blockIdx.x << 6;
  const int b  = mB >> 14;
  const int p0 = mB & 16383;
  const int hrow = p0 >> 7, w0 = p0 & 127;
  const int winb = b*256 + (hrow>>3)*16 + (w0>>3);
  const int tokrow = (hrow & 7)*8;
  const size_t pbase = (size_t)b * (64*16384) + p0;

  float4 f0, f1, f2, f3;
  auto stage_load = [&](const float* plane){
    const float* src = plane + (size_t)((tid>>4)*4)*16384 + (tid&15)*4;
    f0 = *(const float4*)(src);
    f1 = *(const float4*)(src + 16384);
    f2 = *(const float4*)(src + 32768);
    f3 = *(const float4*)(src + 49152);
  };
  auto stage_store = [&](){
    const int tq = tid & 15, c4 = (tid >> 4) * 4;
    #pragma unroll
    for (int j=0;j<4;++j){
      int tok = tq*4 + j;
      int kk = c4 ^ (((tok>>1)&7)<<3);
      uint2 u;
      u.x = pk2(fc(f0,j), fc(f1,j));
      u.y = pk2(fc(f2,j), fc(f3,j));
      *(uint2*)(astg + tok*72 + kk) = u;
    }
  };

  floatx4 c[4][4];
  auto zeroc = [&](){
    #pragma unroll
    for (int mt=0;mt<4;++mt)
      #pragma unroll
      for (int nt=0;nt<4;++nt) c[mt][nt] = (floatx4){0.f,0.f,0.f,0.f};
  };
  auto conv_step = [&](const unsigned short* wf, int KS, int ksg0){
    #pragma unroll
    for (int ksl=0; ksl<2; ++ksl){
      bhalf8 a[4];
      #pragma unroll
      for (int mt=0;mt<4;++mt){
        int tok = mt*16 + col;
        int kk = (ksl*32 + (quad<<3)) ^ (((tok>>1)&7)<<3);
        a[mt] = *(const bhalf8*)(astg + tok*72 + kk);
      }
      #pragma unroll
      for (int nt=0;nt<4;++nt){
        bhalf8 bfr = *(const bhalf8*)(wf + (size_t)(((wave*4+nt)*KS + ksg0 + ksl)*64 + lane)*8);
        #pragma unroll
        for (int mt=0;mt<4;++mt)
          c[mt][nt] = __builtin_amdgcn_mfma_f32_16x16x32_bf16(a[mt], bfr, c[mt][nt], 0, 0, 0);
      }
    }
  };
  auto ln_frag = [&](const float* bias, const float* g, const float* bb2, unsigned short* dst){
    float bv[4];
    #pragma unroll
    for (int nt=0;nt<4;++nt) bv[nt] = bias[wave*64 + nt*16 + col];
    #pragma unroll
    for (int mt=0;mt<4;++mt){
      #pragma unroll
      for (int r=0;r<4;++r){
        float s=0.f, q=0.f;
        #pragma unroll
        for (int nt=0;nt<4;++nt){
          float v = c[mt][nt][r] + bv[nt];
          c[mt][nt][r] = v; s += v; q += v*v;
        }
        s += __shfl_xor(s,1); q += __shfl_xor(q,1);
        s += __shfl_xor(s,2); q += __shfl_xor(q,2);
        s += __shfl_xor(s,4); q += __shfl_xor(q,4);
        s += __shfl_xor(s,8); q += __shfl_xor(q,8);
        if (col == 0){
          int tok = mt*16 + quad*4 + r;
          part[(wave*64+tok)*2+0] = s;
          part[(wave*64+tok)*2+1] = q;
        }
      }
    }
    __syncthreads();
    if (tid < 64){
      float s=0.f, q=0.f;
      #pragma unroll
      for (int w2=0;w2<4;++w2){ s += part[(w2*64+tid)*2]; q += part[(w2*64+tid)*2+1]; }
      float mean = s*(1.f/256.f);
      float var  = q*(1.f/256.f) - mean*mean;
      stats[tid*2]   = mean;
      stats[tid*2+1] = rsqrtf(var + 1e-5f);
    }
    __syncthreads();
    float gv[4], av[4];
    #pragma unroll
    for (int nt=0;nt<4;++nt){ int ch = wave*64+nt*16+col; gv[nt] = g[ch]; av[nt] = bb2[ch]; }
    #pragma unroll
    for (int mt=0;mt<4;++mt)
      #pragma unroll
      for (int r=0;r<4;++r){
        int tok = mt*16 + quad*4 + r;
        float mean = stats[tok*2], rstd = stats[tok*2+1];
        #pragma unroll
        for (int nt=0;nt<4;++nt)
          dst[tok*264 + wave*64 + nt*16 + col] = f2bf((c[mt][nt][r]-mean)*rstd*gv[nt] + av[nt]);
      }
    __syncthreads();
  };

  auto gemm = [&](const unsigned short* Abuf, const unsigned short* wf, const float* bias){
    #pragma unroll
    for (int mt=0;mt<4;++mt)
      #pragma unroll
      for (int nt=0;nt<4;++nt) c[mt][nt] = (floatx4){0.f,0.f,0.f,0.f};
    #pragma unroll
    for (int ks=0; ks<8; ++ks){
      bhalf8 a[4];
      #pragma unroll
      for (int mt=0;mt<4;++mt)
        a[mt] = *(const bhalf8*)(Abuf + (mt*16+col)*264 + ks*32 + (quad<<3));
      #pragma unroll
      for (int nt=0;nt<4;++nt){
        bhalf8 bf = *(const bhalf8*)(wf + (size_t)(((wave*4+nt)*8 + ks)*64 + lane)*8);
        #pragma unroll
        for (int mt=0;mt<4;++mt)
          c[mt][nt] = __builtin_amdgcn_mfma_f32_16x16x32_bf16(a[mt], bf, c[mt][nt], 0, 0, 0);
      }
    }
    #pragma unroll
    for (int nt=0;nt<4;++nt){
      float bb2 = bias[wave*64 + nt*16 + col];
      #pragma unroll
      for (int mt=0;mt<4;++mt)
        #pragma unroll
        for (int r=0;r<4;++r) c[mt][nt][r] += bb2;
    }
  };
  auto stage_write = [&](unsigned short* gout){
    __syncthreads();   // prior readers of sbufA / astg done
    #pragma unroll
    for (int mt=0;mt<4;++mt)
      #pragma unroll
      for (int nt=0;nt<4;++nt)
        #pragma unroll
        for (int r=0;r<4;++r)
          sbufA[(mt*16+quad*4+r)*264 + wave*64 + nt*16 + col] = f2bf(c[mt][nt][r]);
    __syncthreads();
    int tok = tid >> 2, c0 = (tid & 3)*64;
    const uint4* s = (const uint4*)(sbufA + tok*264 + c0);
    uint4* d = (uint4*)(gout + ((size_t)(winb + (tok>>3)))*16384
                             + (size_t)(tokrow + (tok&7))*256 + c0);
    #pragma unroll
    for (int i=0;i<8;++i) d[i] = s[i];
  };

  // ---- z0 conv (HH, K=64) ----
  stage_load(HH + pbase);
  stage_store();
  __syncthreads();
  stage_load(LH + pbase);           // in flight over conv-z
  zeroc(); conv_step(wzf, 2, 0);
  {
    #pragma unroll
    for (int nt=0;nt<4;++nt){
      float bzv = bz[wave*64 + nt*16 + col];
      #pragma unroll
      for (int mt=0;mt<4;++mt)
        #pragma unroll
        for (int r=0;r<4;++r) c[mt][nt][r] += bzv;
    }
  }
  stage_write(z0);                  // z0 window-major
  stage_store();                    // LH -> astg (conv-z reads synced inside stage_write)
  __syncthreads();
  // ---- x conv (LH||HL, K=128) ----
  stage_load(HL + pbase);           // in flight over conv-x ks 0,1
  zeroc(); conv_step(wxf, 4, 0);
  __syncthreads();
  stage_store();                    // HL -> astg
  __syncthreads();
  stage_load(Sp + pbase);           // in flight over conv-x ks 2,3 + LN-x
  conv_step(wxf, 4, 2);
  __syncthreads();                  // astg reads done
  stage_store();                    // Sp -> astg (overlaps LN-x)
  ln_frag(bx, g1x, b1x, sbufA);     // xn
  // ---- y conv (Spat, K=64) ----
  zeroc(); conv_step(wyf, 2, 0);
  ln_frag(by, g1y, b1y, sbufB);     // yn
  // ---- QKV MFMA GEMMs ----
  gemm(sbufA, wqf, bq);
  stage_write(qg);
  gemm(sbufB, wkf, bk);
  stage_write(kg);
  gemm(sbufB, wvf, bv);
  // vt: transposed staging [256 ch][72] then per-window uint4 writes
  __syncthreads();
  #pragma unroll
  for (int mt=0;mt<4;++mt)
    #pragma unroll
    for (int nt=0;nt<4;++nt){
      int ch = wave*64 + nt*16 + col;
      uint2 u; u.x = pk2(c[mt][nt][0], c[mt][nt][1]); u.y = pk2(c[mt][nt][2], c[mt][nt][3]);
      *(uint2*)(sbufA + ch*72 + mt*16 + quad*4) = u;
    }
  __syncthreads();
  {
    int ch = tid;
    #pragma unroll
    for (int wi=0; wi<8; ++wi){
      uint4 val = *(const uint4*)(sbufA + ch*72 + wi*8);
      *(uint4*)(vtg + ((size_t)(winb + wi))*16384 + ch*64 + tokrow) = val;
    }
  }
}

// ---------- kernel 2: MFMA window attention + proj GEMM + z0 residual (fused) ----------
// zt is BF16, window-linear, written over the dead kg bytes of this same window
// (race-free: all k reads of this window precede the post-attention barrier).
__global__ __launch_bounds__(256, 2) void k_attnproj(
    const unsigned short* __restrict__ qg, const unsigned short* kg,
    const unsigned short* vtg, const float* __restrict__ biasf,
    const unsigned short* __restrict__ wpf, const float* __restrict__ bp,
    const unsigned short* __restrict__ z0, unsigned short* kvz)
{
  __shared__ __align__(16) unsigned short Pb[4*64*72];
  __shared__ __align__(16) unsigned short Ob[64*264];
  const int tid = threadIdx.x, lane = tid & 63, wave = tid >> 6;
  const int col = lane & 15, quad = lane >> 4;
  const int win = blockIdx.x;
  const size_t wbase = (size_t)win * 16384;
  const unsigned short* qw = qg + wbase;
  const unsigned short* kw = kg + wbase;
  const unsigned short* vw = vtg + wbase;
  unsigned short* Pw = Pb + wave*64*72;

  #pragma unroll 1
  for (int hh=0; hh<2; ++hh){
    const int h = wave*2 + hh;
    bhalf8 qf[4], kf[4];
    #pragma unroll
    for (int mt=0;mt<4;++mt)
      qf[mt] = *(const bhalf8*)(qw + (mt*16+col)*256 + h*32 + (quad<<3));
    #pragma unroll
    for (int nt=0;nt<4;++nt)
      kf[nt] = *(const bhalf8*)(kw + (nt*16+col)*256 + h*32 + (quad<<3));
    floatx4 S[4][4];
    #pragma unroll
    for (int mt=0;mt<4;++mt)
      #pragma unroll
      for (int nt=0;nt<4;++nt) S[mt][nt] = (floatx4){0.f,0.f,0.f,0.f};
    #pragma unroll
    for (int mt=0;mt<4;++mt)
      #pragma unroll
      for (int nt=0;nt<4;++nt)
        S[mt][nt] = __builtin_amdgcn_mfma_f32_16x16x32_bf16(qf[mt], kf[nt], S[mt][nt], 0, 0, 0);
    #pragma unroll
    for (int mt=0;mt<4;++mt)
      #pragma unroll
      for (int nt=0;nt<4;++nt){
        float4 bb = *(const float4*)(biasf + (size_t)(((h*4+mt)*4+nt))*256 + lane*4);
        S[mt][nt][0] += bb.x; S[mt][nt][1] += bb.y; S[mt][nt][2] += bb.z; S[mt][nt][3] += bb.w;
      }
    float linv[4][4];
    #pragma unroll
    for (int mt=0;mt<4;++mt){
      #pragma unroll
      for (int r=0;r<4;++r){
        float mx = fmaxf(fmaxf(S[mt][0][r], S[mt][1][r]), fmaxf(S[mt][2][r], S[mt][3][r]));
        mx = fmaxf(mx, __shfl_xor(mx, 1));
        mx = fmaxf(mx, __shfl_xor(mx, 2));
        mx = fmaxf(mx, __shfl_xor(mx, 4));
        mx = fmaxf(mx, __shfl_xor(mx, 8));
        float e0 = __expf(S[mt][0][r]-mx), e1 = __expf(S[mt][1][r]-mx);
        float e2 = __expf(S[mt][2][r]-mx), e3 = __expf(S[mt][3][r]-mx);
        S[mt][0][r]=e0; S[mt][1][r]=e1; S[mt][2][r]=e2; S[mt][3][r]=e3;
        float l = e0+e1+e2+e3;
        l += __shfl_xor(l, 1);
        l += __shfl_xor(l, 2);
        l += __shfl_xor(l, 4);
        l += __shfl_xor(l, 8);
        linv[mt][r] = 1.f/l;
      }
    }
    #pragma unroll
    for (int mt=0;mt<4;++mt)
      #pragma unroll
      for (int nt=0;nt<4;++nt)
        #pragma unroll
        for (int r=0;r<4;++r)
          Pw[(mt*16+quad*4+r)*72 + nt*16 + col] = f2bf(S[mt][nt][r]);
    asm volatile("s_waitcnt lgkmcnt(0)" ::: "memory");
    floatx4 O[4][2];
    #pragma unroll
    for (int mt=0;mt<4;++mt){ O[mt][0]=(floatx4){0.f,0.f,0.f,0.f}; O[mt][1]=(floatx4){0.f,0.f,0.f,0.f}; }
    #pragma unroll
    for (int ks=0; ks<2; ++ks){
      bhalf8 vf[2];
      #pragma unroll
      for (int nt2=0;nt2<2;++nt2)
        vf[nt2] = *(const bhalf8*)(vw + (h*32 + nt2*16 + col)*64 + ks*32 + (quad<<3));
      #pragma unroll
      for (int mt=0;mt<4;++mt){
        bhalf8 pf = *(const bhalf8*)(Pw + (mt*16+col)*72 + ks*32 + (quad<<3));
        #pragma unroll
        for (int nt2=0;nt2<2;++nt2)
          O[mt][nt2] = __builtin_amdgcn_mfma_f32_16x16x32_bf16(pf, vf[nt2], O[mt][nt2], 0, 0, 0);
      }
    }
    #pragma unroll
    for (int mt=0;mt<4;++mt)
      #pragma unroll
      for (int nt2=0;nt2<2;++nt2)
        #pragma unroll
        for (int r=0;r<4;++r)
          Ob[(mt*16+quad*4+r)*264 + h*32 + nt2*16 + col] = f2bf(O[mt][nt2][r]*linv[mt][r]);
  }
  __syncthreads();   // all k/v reads + Ob writes complete

  // ---- proj GEMM: A = Ob (LDS), B = wpf ----
  floatx4 c[4][4];
  #pragma unroll
  for (int mt=0;mt<4;++mt)
    #pragma unroll
    for (int nt=0;nt<4;++nt) c[mt][nt] = (floatx4){0.f,0.f,0.f,0.f};
  #pragma unroll
  for (int ks=0; ks<8; ++ks){
    bhalf8 a[4];
    #pragma unroll
    for (int mt=0;mt<4;++mt)
      a[mt] = *(const bhalf8*)(Ob + (mt*16+col)*264 + ks*32 + (quad<<3));
    #pragma unroll
    for (int nt=0;nt<4;++nt){
      bhalf8 bf = *(const bhalf8*)(wpf + (size_t)(((wave*4+nt)*8 + ks)*64 + lane)*8);
      #pragma unroll
      for (int mt=0;mt<4;++mt)
        c[mt][nt] = __builtin_amdgcn_mfma_f32_16x16x32_bf16(a[mt], bf, c[mt][nt], 0, 0, 0);
    }
  }
  float bb[4];
  #pragma unroll
  for (int nt=0;nt<4;++nt) bb[nt] = bp[wave*64 + nt*16 + col];

  float* obuf = (float*)Pb;                        // [32][260] overlay, Pb is dead
  unsigned short* ztb = kvz + (size_t)win * 16384; // bf16 zt, window-linear over kg bytes
  #pragma unroll 1
  for (int p=0; p<2; ++p){
    __syncthreads();
    #pragma unroll
    for (int mt2=0;mt2<2;++mt2){
      int mt = p*2 + mt2;
      #pragma unroll
      for (int nt=0;nt<4;++nt)
        #pragma unroll
        for (int r=0;r<4;++r)
          obuf[(mt2*16+quad*4+r)*260 + wave*64 + nt*16 + col] = c[mt][nt][r] + bb[nt];
    }
    __syncthreads();
    {
      int tl = tid >> 3, c0 = (tid & 7)*32;
      int tok = p*32 + tl;
      const float4* s = (const float4*)(obuf + tl*260 + c0);
      const uint4* zp = (const uint4*)(z0 + ((size_t)win*64 + tok)*256 + c0);
      float zv[32];
      #pragma unroll
      for (int i=0;i<4;++i) unpack8(zp[i], zv + i*8);
      uint4* d = (uint4*)(ztb + (size_t)tok*256 + c0);
      #pragma unroll
      for (int i=0;i<4;++i){
        float4 a = s[2*i], b4 = s[2*i+1];
        float r0 = a.x  + zv[i*8+0], r1 = a.y  + zv[i*8+1];
        float r2 = a.z  + zv[i*8+2], r3 = a.w  + zv[i*8+3];
        float r4 = b4.x + zv[i*8+4], r5 = b4.y + zv[i*8+5];
        float r6 = b4.z + zv[i*8+6], r7 = b4.w + zv[i*8+7];
        uint4 u;
        u.x = pk2(r0,r1); u.y = pk2(r2,r3); u.z = pk2(r4,r5); u.w = pk2(r6,r7);
        d[i] = u;
      }
    }
  }
}

// ---------- kernel 3: LN2 + MFMA MLP + residual + NCHW transpose ----------
// zt read as bf16 window-linear from the kv region. Restructured for occupancy:
// LDS 50688 B (3 blocks/CU): ztn[64][264] + double-buffered hbuf[2][16][264],
// per-(hb,mt) fc1->fc2 phases with a single barrier each (fc2(mt) overlaps fc1(mt+1)).
__global__ __launch_bounds__(256, 3) void k_mlp(
    const unsigned short* __restrict__ kvzt,
    const float* __restrict__ g2, const float* __restrict__ b2,
    const unsigned short* __restrict__ w1f, const float* __restrict__ fc1b,
    const unsigned short* __restrict__ w2f, const float* __restrict__ fc2b,
    float* __restrict__ out)
{
  __shared__ __align__(16) unsigned short smu[96*264];  // ztn[64][264] + hbuf[2][16][264]
  unsigned short* ztn = smu;
  float* ob = (float*)smu;   // epilogue overlay [32][257] f32 (32896 B < 33792 B ztn)

  const int tid  = threadIdx.x;
  const int mB   = blockIdx.x << 6;
  const int lane = tid & 63, wave = tid >> 6;
  const int col  = lane & 15, quad = lane >> 4;

  const int bb_ = mB >> 14;
  const int pp0 = mB & 16383;
  const int hrow = pp0 >> 7, w0 = pp0 & 127;
  const int winb = bb_*256 + (hrow>>3)*16 + (w0>>3);
  const int tokrow = (hrow & 7)*8;
  auto ztrow = [&](int tok)->size_t{
    return ((size_t)(winb + (tok>>3))*64 + (size_t)(tokrow + (tok&7))) * 256;
  };

  // ---- LN2 (bf16 zt in) ----
  {
    const int tok = tid >> 2, qd = tid & 3;
    const uint4* zr = (const uint4*)(kvzt + ztrow(tok) + qd*64);
    float v[64];
    #pragma unroll
    for (int j=0;j<8;++j) unpack8(zr[j], v + j*8);
    float s=0.f, q=0.f;
    #pragma unroll
    for (int j=0;j<64;++j){ s += v[j]; q += v[j]*v[j]; }
    s += __shfl_xor(s,1); q += __shfl_xor(q,1);
    s += __shfl_xor(s,2); q += __shfl_xor(q,2);
    float mean = s*(1.f/256.f);
    float rstd = rsqrtf(q*(1.f/256.f) - mean*mean + 1e-5f);
    float gv[64], bv[64];
    #pragma unroll
    for (int j4=0;j4<16;++j4){
      float4 t = ((const float4*)(g2 + qd*64))[j4];
      gv[j4*4+0]=t.x; gv[j4*4+1]=t.y; gv[j4*4+2]=t.z; gv[j4*4+3]=t.w;
      float4 u = ((const float4*)(b2 + qd*64))[j4];
      bv[j4*4+0]=u.x; bv[j4*4+1]=u.y; bv[j4*4+2]=u.z; bv[j4*4+3]=u.w;
    }
    unsigned short* zd = ztn + tok*264 + qd*64;
    #pragma unroll
    for (int j8=0;j8<8;++j8){
      float r[8];
      #pragma unroll
      for (int e=0;e<8;++e) r[e] = (v[j8*8+e]-mean)*rstd*gv[j8*8+e] + bv[j8*8+e];
      uint4 u;
      u.x=pk2(r[0],r[1]); u.y=pk2(r[2],r[3]); u.z=pk2(r[4],r[5]); u.w=pk2(r[6],r[7]);
      *(uint4*)(zd + j8*8) = u;
    }
  }
  __syncthreads();

  floatx4 oacc[4][4];
  #pragma unroll
  for (int i=0;i<4;++i)
    #pragma unroll
    for (int j=0;j<4;++j) oacc[i][j] = (floatx4){0.f,0.f,0.f,0.f};

  #pragma unroll 1
  for (int hb=0; hb<4; ++hb){
    float bv1[4];
    #pragma unroll
    for (int nt=0;nt<4;++nt) bv1[nt] = fc1b[hb*256 + wave*64 + nt*16 + col];
    #pragma unroll
    for (int mt=0; mt<4; ++mt){
      unsigned short* hb16 = smu + 64*264 + (mt & 1)*16*264;   // double-buffered [16][264]
      // fc1 (16 tokens x 256 hid of this hb)
      floatx4 hacc[4];
      #pragma unroll
      for (int nt=0;nt<4;++nt) hacc[nt] = (floatx4){0.f,0.f,0.f,0.f};
      #pragma unroll
      for (int ks=0; ks<8; ++ks){
        bhalf8 a = *(const bhalf8*)(ztn + (mt*16 + col)*264 + ks*32 + (quad<<3));
        #pragma unroll
        for (int nt=0; nt<4; ++nt){
          int gnt = hb*16 + wave*4 + nt;
          bhalf8 b = *(const bhalf8*)(w1f + (size_t)((gnt*8 + ks)*64 + lane)*8);
          hacc[nt] = __builtin_amdgcn_mfma_f32_16x16x32_bf16(a, b, hacc[nt], 0, 0, 0);
        }
      }
      #pragma unroll
      for (int nt=0; nt<4; ++nt){
        int ch = wave*64 + nt*16 + col;
        #pragma unroll
        for (int r=0;r<4;++r)
          hb16[(quad*4 + r)*264 + ch] = f2bf(gelu(hacc[nt][r] + bv1[nt]));
      }
      __syncthreads();
      // fc2 (accumulate this hb's 256-hid slice into oacc[mt])
      #pragma unroll
      for (int ks=0; ks<8; ++ks){
        bhalf8 a = *(const bhalf8*)(hb16 + col*264 + ks*32 + (quad<<3));
        #pragma unroll
        for (int ot=0; ot<4; ++ot){
          int go = wave*4 + ot;
          bhalf8 b = *(const bhalf8*)(w2f + (size_t)((go*32 + hb*8 + ks)*64 + lane)*8);
          oacc[mt][ot] = __builtin_amdgcn_mfma_f32_16x16x32_bf16(a, b, oacc[mt][ot], 0, 0, 0);
        }
      }
      // no trailing barrier: next fc1 writes the other hbuf half; the next phase's
      // barrier orders reuse of this half (readers done before overwrite 2 phases later)
    }
  }

  // ---- epilogue: bias + residual (bf16 zt) + NCHW transpose, 32 tokens per pass ----
  float bo[4];
  #pragma unroll
  for (int ot=0;ot<4;++ot) bo[ot] = fc2b[wave*64 + ot*16 + col];
  const int bgl = mB >> 14, hw0 = mB & 16383;
  #pragma unroll 1
  for (int p=0; p<2; ++p){
    __syncthreads();   // prior ztn/hbuf reads (p=0) or ob scatter reads (p=1) done
    #pragma unroll
    for (int mt2=0; mt2<2; ++mt2){
      int mt = p*2 + mt2;
      #pragma unroll
      for (int ot=0; ot<4; ++ot){
        int ch = wave*64 + ot*16 + col;
        #pragma unroll
        for (int r=0;r<4;++r){
          int tok = mt*16 + quad*4 + r;
          float zv = bflo((unsigned)kvzt[ztrow(tok) + ch]);
          ob[(mt2*16 + quad*4 + r)*257 + ch] = oacc[mt][ot][r] + bo[ot] + zv;
        }
      }
    }
    __syncthreads();
    float* obase = out + (size_t)bgl*(256*16384) + hw0 + p*32;
    #pragma unroll 1
    for (int it=0; it<32; ++it){
      int l = it*256 + tid;
      int o = l >> 5, tk = l & 31;
      obase[(size_t)o*16384 + tk] = ob[tk*257 + o];
    }
  }
}

// ---------- host ----------
extern "C" void kernel_launch(void* const* d_in, const int* in_sizes, int n_in,
                              void* d_out, int out_size, void* d_ws, size_t ws_size,
                              hipStream_t stream)
{
  (void)in_sizes; (void)n_in; (void)out_size; (void)ws_size;
  const float* LH    = (const float*)d_in[0];
  const float* HL    = (const float*)d_in[1];
  const float* HH    = (const float*)d_in[2];
  const float* Spat  = (const float*)d_in[3];
  const float* w_hllh= (const float*)d_in[4];
  const float* b_hllh= (const float*)d_in[5];
  const float* w_hh  = (const float*)d_in[6];
  const float* b_hh  = (const float*)d_in[7];
  const float* w_spat= (const float*)d_in[8];
  const float* b_spat= (const float*)d_in[9];
  const float* ln1x_g= (const float*)d_in[10];
  const float* ln1x_b= (const float*)d_in[11];
  const float* ln1y_g= (const float*)d_in[12];
  const float* ln1y_b= (const float*)d_in[13];
  const float* qkv_w = (const float*)d_in[14];
  const float* qkv_b = (const float*)d_in[15];
  const float* qkv2_w= (const float*)d_in[16];
  const float* qkv2_b= (const float*)d_in[17];
  const float* qkv3_w= (const float*)d_in[18];
  const float* qkv3_b= (const float*)d_in[19];
  const float* proj_w= (const float*)d_in[20];
  const float* proj_b= (const float*)d_in[21];
  const float* rpb   = (const float*)d_in[22];
  const float* ln2_g = (const float*)d_in[23];
  const float* ln2_b = (const float*)d_in[24];
  const float* fc1_w = (const float*)d_in[25];
  const float* fc1_b = (const float*)d_in[26];
  const float* fc2_w = (const float*)d_in[27];
  const float* fc2_b = (const float*)d_in[28];
  float* out = (float*)d_out;

  char* ws = (char*)d_ws;
  size_t off = 0;
  auto alloc = [&](size_t bytes)->void*{
    void* p = ws + off; off += (bytes + 255) & ~(size_t)255; return p;
  };
  const size_t M = 131072;
  unsigned short* z0  = (unsigned short*)alloc(M*256*2);   // window-major bf16
  unsigned short* qg  = (unsigned short*)alloc(M*256*2);
  char* kv_region     = (char*)alloc(M*256*4);   // kg | vtg ; kg bytes reused as bf16 zt
  unsigned short* kg  = (unsigned short*)kv_region;
  unsigned short* vtg = (unsigned short*)(kv_region + M*256*2);
  unsigned short* ztb = (unsigned short*)kv_region;   // bf16 zt, window-linear
  unsigned short* wxf = (unsigned short*)alloc(256*128*2);
  unsigned short* wzf = (unsigned short*)alloc(256*64*2);
  unsigned short* wyf = (unsigned short*)alloc(256*64*2);
  unsigned short* wqf = (unsigned short*)alloc(256*256*2);
  unsigned short* wkf = (unsigned short*)alloc(256*256*2);
  unsigned short* wvf = (unsigned short*)alloc(256*256*2);
  unsigned short* wpf = (unsigned short*)alloc(256*256*2);
  unsigned short* w1f = (unsigned short*)alloc(1024*256*2);
  unsigned short* w2f = (unsigned short*)alloc(256*1024*2);
  float* biasf = (float*)alloc(32768*4);
  float* bqs = (float*)alloc(256*4);

  const float sc = 0.17677669529663687f;  // 1/sqrt(hd=32), folded into q weights+bias
  k_fragw<<<dim3(128),  dim3(256), 0, stream>>>(w_hllh, wxf, 256*128, 128, 1.f);
  k_fragw<<<dim3(64),   dim3(256), 0, stream>>>(w_hh,   wzf, 256*64,  64,  1.f);
  k_fragw<<<dim3(64),   dim3(256), 0, stream>>>(w_spat, wyf, 256*64,  64,  1.f);
  k_fragw<<<dim3(256),  dim3(256), 0, stream>>>(qkv_w,  wqf, 256*256, 256, sc);
  k_fragw<<<dim3(256),  dim3(256), 0, stream>>>(qkv2_w, wkf, 256*256, 256, 1.f);
  k_fragw<<<dim3(256),  dim3(256), 0, stream>>>(qkv3_w, wvf, 256*256, 256, 1.f);
  k_fragw<<<dim3(256),  dim3(256), 0, stream>>>(proj_w, wpf, 256*256, 256, 1.f);
  k_fragw<<<dim3(1024), dim3(256), 0, stream>>>(fc1_w,  w1f, 1024*256, 256, 1.f);
  k_fragw<<<dim3(1024), dim3(256), 0, stream>>>(fc2_w,  w2f, 256*1024, 1024, 1.f);
  k_bias <<<dim3(128),  dim3(256), 0, stream>>>(rpb, biasf);
  k_scale_vec<<<dim3(1), dim3(256), 0, stream>>>(qkv_b, bqs, 256, sc);

  k_front<<<dim3(2048), dim3(256), 0, stream>>>(LH, HL, HH, Spat,
      wxf, b_hllh, wzf, b_hh, wyf, b_spat,
      ln1x_g, ln1x_b, ln1y_g, ln1y_b,
      wqf, bqs, wkf, qkv2_b, wvf, qkv3_b,
      z0, qg, kg, vtg);
  k_attnproj<<<dim3(2048), dim3(256), 0, stream>>>(qg, kg, vtg, biasf, wpf, proj_b, z0, ztb);
  k_mlp<<<dim3(2048), dim3(256), 0, stream>>>(ztb, ln2_g, ln2_b,
      w1f, fc1_b, w2f, fc2_b, out);
}

// Round 8
// 1412.146 us; speedup vs baseline: 1.0870x; 1.0870x over previous
//
#include <hip/hip_runtime.h>
#include <math.h>

#define DI static __device__ __forceinline__

typedef __attribute__((ext_vector_type(8))) short bhalf8;
typedef __attribute__((ext_vector_type(4))) float floatx4;

// ---------- bf16 helpers ----------
DI unsigned short f2bf(float f){
  union { float f; unsigned u; } v; v.f = f;
  unsigned r = (v.u + 0x7fffu + ((v.u >> 16) & 1u)) >> 16;
  return (unsigned short)r;
}
DI float bflo(unsigned v){ return __uint_as_float(v << 16); }
DI float bfhi(unsigned v){ return __uint_as_float(v & 0xffff0000u); }
DI unsigned pk2(float a, float b){ return (unsigned)f2bf(a) | ((unsigned)f2bf(b) << 16); }
DI void unpack8(uint4 u, float* a){
  a[0]=bflo(u.x); a[1]=bfhi(u.x); a[2]=bflo(u.y); a[3]=bfhi(u.y);
  a[4]=bflo(u.z); a[5]=bfhi(u.z); a[6]=bflo(u.w); a[7]=bfhi(u.w);
}
DI float fc(float4 v, int j){ return j==0 ? v.x : (j==1 ? v.y : (j==2 ? v.z : v.w)); }
// tanh-form GELU: max |err| vs exact ~3e-4
DI float gelu(float x){
  float u = x*(0.7978845608f + 0.0356774081f*x*x);
  float e = __expf(2.f*u);
  return x - x/(e + 1.f);
}

// ---------- prep kernels ----------
__global__ void k_scale_vec(const float* __restrict__ src, float* __restrict__ dst, int n, float s){
  int i = blockIdx.x*256 + threadIdx.x;
  if (i < n) dst[i] = src[i]*s;
}
// pack weight (O x K f32 row-major) into bf16 MFMA B-fragment order
__global__ void k_fragw(const float* __restrict__ src, unsigned short* __restrict__ dst,
                        int n, int K, float scale){
  int t = blockIdx.x*256 + threadIdx.x;
  if (t >= n) return;
  int j = t & 7, lane = (t >> 3) & 63, rest = t >> 9;
  int KS = K >> 5;
  int ks = rest % KS, nt = rest / KS;
  int row = nt*16 + (lane & 15);
  int col = ks*32 + ((lane >> 4) << 3) + j;
  dst[t] = f2bf(src[(size_t)row*K + col] * scale);
}
// relative-position bias in C-fragment layout: biasf[((h*4+mt)*4+nt)*256 + lane*4 + r]
__global__ void k_bias(const float* __restrict__ rpb, float* __restrict__ biasf){
  int t = blockIdx.x*256 + threadIdx.x;   // 32768 total
  int r = t & 3, lane = (t>>2) & 63, nt = (t>>8) & 3, mt = (t>>10) & 3, h = t>>12;
  int qtok = mt*16 + (lane>>4)*4 + r;
  int ktok = nt*16 + (lane & 15);
  int idx = ((qtok>>3) - (ktok>>3) + 7)*15 + ((qtok&7) - (ktok&7) + 7);
  biasf[t] = rpb[idx*8 + h];
}

// ---------- kernel 1: MFMA convs + LN1 + QKV MFMA GEMMs (unchanged) ----------
__global__ __launch_bounds__(256) void k_front(
    const float* __restrict__ LH, const float* __restrict__ HL,
    const float* __restrict__ HH, const float* __restrict__ Sp,
    const unsigned short* __restrict__ wxf, const float* __restrict__ bx,
    const unsigned short* __restrict__ wzf, const float* __restrict__ bz,
    const unsigned short* __restrict__ wyf, const float* __restrict__ by,
    const float* __restrict__ g1x, const float* __restrict__ b1x,
    const float* __restrict__ g1y, const float* __restrict__ b1y,
    const unsigned short* __restrict__ wqf, const float* __restrict__ bq,
    const unsigned short* __restrict__ wkf, const float* __restrict__ bk,
    const unsigned short* __restrict__ wvf, const float* __restrict__ bv,
    unsigned short* __restrict__ z0, unsigned short* __restrict__ qg,
    unsigned short* __restrict__ kg, unsigned short* __restrict__ vtg)
{
  __shared__ __align__(16) unsigned short astg[64*72];    // 9216B conv-A staging (one 64ch plane)
  __shared__ __align__(16) unsigned short sbufA[64*288];  // xn [64][264] / staging / vt [256][72]
  __shared__ __align__(16) unsigned short sbufB[64*264];  // yn [64][264]
  // LN scratch lives in sbufA tail bytes [33792, 36352): rows only use up to 16887 ushorts
  float* part  = (float*)(sbufA + 16896);   // [256][2]
  float* stats = part + 512;                // [64][2]

  const int tid = threadIdx.x;
  const int lane = tid & 63, wave = tid >> 6, col = lane & 15, quad = lane >> 4;
  const int mB = blockIdx.x << 6;
  const int b  = mB >> 14;
  const int p0 = mB & 16383;
  const int hrow = p0 >> 7, w0 = p0 & 127;
  const int winb = b*256 + (hrow>>3)*16 + (w0>>3);
  const int tokrow = (hrow & 7)*8;
  const size_t pbase = (size_t)b * (64*16384) + p0;

  float4 f0, f1, f2, f3;
  auto stage_load = [&](const float* plane){
    const float* src = plane + (size_t)((tid>>4)*4)*16384 + (tid&15)*4;
    f0 = *(const float4*)(src);
    f1 = *(const float4*)(src + 16384);
    f2 = *(const float4*)(src + 32768);
    f3 = *(const float4*)(src + 49152);
  };
  auto stage_store = [&](){
    const int tq = tid & 15, c4 = (tid >> 4) * 4;
    #pragma unroll
    for (int j=0;j<4;++j){
      int tok = tq*4 + j;
      int kk = c4 ^ (((tok>>1)&7)<<3);
      uint2 u;
      u.x = pk2(fc(f0,j), fc(f1,j));
      u.y = pk2(fc(f2,j), fc(f3,j));
      *(uint2*)(astg + tok*72 + kk) = u;
    }
  };

  floatx4 c[4][4];
  auto zeroc = [&](){
    #pragma unroll
    for (int mt=0;mt<4;++mt)
      #pragma unroll
      for (int nt=0;nt<4;++nt) c[mt][nt] = (floatx4){0.f,0.f,0.f,0.f};
  };
  auto conv_step = [&](const unsigned short* wf, int KS, int ksg0){
    #pragma unroll
    for (int ksl=0; ksl<2; ++ksl){
      bhalf8 a[4];
      #pragma unroll
      for (int mt=0;mt<4;++mt){
        int tok = mt*16 + col;
        int kk = (ksl*32 + (quad<<3)) ^ (((tok>>1)&7)<<3);
        a[mt] = *(const bhalf8*)(astg + tok*72 + kk);
      }
      #pragma unroll
      for (int nt=0;nt<4;++nt){
        bhalf8 bfr = *(const bhalf8*)(wf + (size_t)(((wave*4+nt)*KS + ksg0 + ksl)*64 + lane)*8);
        #pragma unroll
        for (int mt=0;mt<4;++mt)
          c[mt][nt] = __builtin_amdgcn_mfma_f32_16x16x32_bf16(a[mt], bfr, c[mt][nt], 0, 0, 0);
      }
    }
  };
  auto ln_frag = [&](const float* bias, const float* g, const float* bb2, unsigned short* dst){
    float bv[4];
    #pragma unroll
    for (int nt=0;nt<4;++nt) bv[nt] = bias[wave*64 + nt*16 + col];
    #pragma unroll
    for (int mt=0;mt<4;++mt){
      #pragma unroll
      for (int r=0;r<4;++r){
        float s=0.f, q=0.f;
        #pragma unroll
        for (int nt=0;nt<4;++nt){
          float v = c[mt][nt][r] + bv[nt];
          c[mt][nt][r] = v; s += v; q += v*v;
        }
        s += __shfl_xor(s,1); q += __shfl_xor(q,1);
        s += __shfl_xor(s,2); q += __shfl_xor(q,2);
        s += __shfl_xor(s,4); q += __shfl_xor(q,4);
        s += __shfl_xor(s,8); q += __shfl_xor(q,8);
        if (col == 0){
          int tok = mt*16 + quad*4 + r;
          part[(wave*64+tok)*2+0] = s;
          part[(wave*64+tok)*2+1] = q;
        }
      }
    }
    __syncthreads();
    if (tid < 64){
      float s=0.f, q=0.f;
      #pragma unroll
      for (int w2=0;w2<4;++w2){ s += part[(w2*64+tid)*2]; q += part[(w2*64+tid)*2+1]; }
      float mean = s*(1.f/256.f);
      float var  = q*(1.f/256.f) - mean*mean;
      stats[tid*2]   = mean;
      stats[tid*2+1] = rsqrtf(var + 1e-5f);
    }
    __syncthreads();
    float gv[4], av[4];
    #pragma unroll
    for (int nt=0;nt<4;++nt){ int ch = wave*64+nt*16+col; gv[nt] = g[ch]; av[nt] = bb2[ch]; }
    #pragma unroll
    for (int mt=0;mt<4;++mt)
      #pragma unroll
      for (int r=0;r<4;++r){
        int tok = mt*16 + quad*4 + r;
        float mean = stats[tok*2], rstd = stats[tok*2+1];
        #pragma unroll
        for (int nt=0;nt<4;++nt)
          dst[tok*264 + wave*64 + nt*16 + col] = f2bf((c[mt][nt][r]-mean)*rstd*gv[nt] + av[nt]);
      }
    __syncthreads();
  };

  auto gemm = [&](const unsigned short* Abuf, const unsigned short* wf, const float* bias){
    #pragma unroll
    for (int mt=0;mt<4;++mt)
      #pragma unroll
      for (int nt=0;nt<4;++nt) c[mt][nt] = (floatx4){0.f,0.f,0.f,0.f};
    #pragma unroll
    for (int ks=0; ks<8; ++ks){
      bhalf8 a[4];
      #pragma unroll
      for (int mt=0;mt<4;++mt)
        a[mt] = *(const bhalf8*)(Abuf + (mt*16+col)*264 + ks*32 + (quad<<3));
      #pragma unroll
      for (int nt=0;nt<4;++nt){
        bhalf8 bf = *(const bhalf8*)(wf + (size_t)(((wave*4+nt)*8 + ks)*64 + lane)*8);
        #pragma unroll
        for (int mt=0;mt<4;++mt)
          c[mt][nt] = __builtin_amdgcn_mfma_f32_16x16x32_bf16(a[mt], bf, c[mt][nt], 0, 0, 0);
      }
    }
    #pragma unroll
    for (int nt=0;nt<4;++nt){
      float bb2 = bias[wave*64 + nt*16 + col];
      #pragma unroll
      for (int mt=0;mt<4;++mt)
        #pragma unroll
        for (int r=0;r<4;++r) c[mt][nt][r] += bb2;
    }
  };
  auto stage_write = [&](unsigned short* gout){
    __syncthreads();   // prior readers of sbufA / astg done
    #pragma unroll
    for (int mt=0;mt<4;++mt)
      #pragma unroll
      for (int nt=0;nt<4;++nt)
        #pragma unroll
        for (int r=0;r<4;++r)
          sbufA[(mt*16+quad*4+r)*264 + wave*64 + nt*16 + col] = f2bf(c[mt][nt][r]);
    __syncthreads();
    int tok = tid >> 2, c0 = (tid & 3)*64;
    const uint4* s = (const uint4*)(sbufA + tok*264 + c0);
    uint4* d = (uint4*)(gout + ((size_t)(winb + (tok>>3)))*16384
                             + (size_t)(tokrow + (tok&7))*256 + c0);
    #pragma unroll
    for (int i=0;i<8;++i) d[i] = s[i];
  };

  // ---- z0 conv (HH, K=64) ----
  stage_load(HH + pbase);
  stage_store();
  __syncthreads();
  stage_load(LH + pbase);           // in flight over conv-z
  zeroc(); conv_step(wzf, 2, 0);
  {
    #pragma unroll
    for (int nt=0;nt<4;++nt){
      float bzv = bz[wave*64 + nt*16 + col];
      #pragma unroll
      for (int mt=0;mt<4;++mt)
        #pragma unroll
        for (int r=0;r<4;++r) c[mt][nt][r] += bzv;
    }
  }
  stage_write(z0);                  // z0 window-major
  stage_store();                    // LH -> astg (conv-z reads synced inside stage_write)
  __syncthreads();
  // ---- x conv (LH||HL, K=128) ----
  stage_load(HL + pbase);           // in flight over conv-x ks 0,1
  zeroc(); conv_step(wxf, 4, 0);
  __syncthreads();
  stage_store();                    // HL -> astg
  __syncthreads();
  stage_load(Sp + pbase);           // in flight over conv-x ks 2,3 + LN-x
  conv_step(wxf, 4, 2);
  __syncthreads();                  // astg reads done
  stage_store();                    // Sp -> astg (overlaps LN-x)
  ln_frag(bx, g1x, b1x, sbufA);     // xn
  // ---- y conv (Spat, K=64) ----
  zeroc(); conv_step(wyf, 2, 0);
  ln_frag(by, g1y, b1y, sbufB);     // yn
  // ---- QKV MFMA GEMMs ----
  gemm(sbufA, wqf, bq);
  stage_write(qg);
  gemm(sbufB, wkf, bk);
  stage_write(kg);
  gemm(sbufB, wvf, bv);
  // vt: transposed staging [256 ch][72] then per-window uint4 writes
  __syncthreads();
  #pragma unroll
  for (int mt=0;mt<4;++mt)
    #pragma unroll
    for (int nt=0;nt<4;++nt){
      int ch = wave*64 + nt*16 + col;
      uint2 u; u.x = pk2(c[mt][nt][0], c[mt][nt][1]); u.y = pk2(c[mt][nt][2], c[mt][nt][3]);
      *(uint2*)(sbufA + ch*72 + mt*16 + quad*4) = u;
    }
  __syncthreads();
  {
    int ch = tid;
    #pragma unroll
    for (int wi=0; wi<8; ++wi){
      uint4 val = *(const uint4*)(sbufA + ch*72 + wi*8);
      *(uint4*)(vtg + ((size_t)(winb + wi))*16384 + ch*64 + tokrow) = val;
    }
  }
}

// ---------- kernel 2: MFMA window attention + proj GEMM + z0 residual (fused) ----------
// zt is BF16, window-linear, written over the dead kg bytes of this same window
// (race-free: all k reads of this window precede the post-attention barrier).
// NOTE: epilogue p-loop is FULLY UNROLLED — a runtime index into c[] would force the
// whole accumulator array to scratch (rule #20; cost measured ~1 GB HBM in round 6).
__global__ __launch_bounds__(256, 2) void k_attnproj(
    const unsigned short* __restrict__ qg, const unsigned short* kg,
    const unsigned short* vtg, const float* __restrict__ biasf,
    const unsigned short* __restrict__ wpf, const float* __restrict__ bp,
    const unsigned short* __restrict__ z0, unsigned short* kvz)
{
  __shared__ __align__(16) unsigned short Pb[4*64*72];
  __shared__ __align__(16) unsigned short Ob[64*264];
  const int tid = threadIdx.x, lane = tid & 63, wave = tid >> 6;
  const int col = lane & 15, quad = lane >> 4;
  const int win = blockIdx.x;
  const size_t wbase = (size_t)win * 16384;
  const unsigned short* qw = qg + wbase;
  const unsigned short* kw = kg + wbase;
  const unsigned short* vw = vtg + wbase;
  unsigned short* Pw = Pb + wave*64*72;

  #pragma unroll 1
  for (int hh=0; hh<2; ++hh){
    const int h = wave*2 + hh;
    bhalf8 qf[4], kf[4];
    #pragma unroll
    for (int mt=0;mt<4;++mt)
      qf[mt] = *(const bhalf8*)(qw + (mt*16+col)*256 + h*32 + (quad<<3));
    #pragma unroll
    for (int nt=0;nt<4;++nt)
      kf[nt] = *(const bhalf8*)(kw + (nt*16+col)*256 + h*32 + (quad<<3));
    floatx4 S[4][4];
    #pragma unroll
    for (int mt=0;mt<4;++mt)
      #pragma unroll
      for (int nt=0;nt<4;++nt) S[mt][nt] = (floatx4){0.f,0.f,0.f,0.f};
    #pragma unroll
    for (int mt=0;mt<4;++mt)
      #pragma unroll
      for (int nt=0;nt<4;++nt)
        S[mt][nt] = __builtin_amdgcn_mfma_f32_16x16x32_bf16(qf[mt], kf[nt], S[mt][nt], 0, 0, 0);
    #pragma unroll
    for (int mt=0;mt<4;++mt)
      #pragma unroll
      for (int nt=0;nt<4;++nt){
        float4 bb = *(const float4*)(biasf + (size_t)(((h*4+mt)*4+nt))*256 + lane*4);
        S[mt][nt][0] += bb.x; S[mt][nt][1] += bb.y; S[mt][nt][2] += bb.z; S[mt][nt][3] += bb.w;
      }
    float linv[4][4];
    #pragma unroll
    for (int mt=0;mt<4;++mt){
      #pragma unroll
      for (int r=0;r<4;++r){
        float mx = fmaxf(fmaxf(S[mt][0][r], S[mt][1][r]), fmaxf(S[mt][2][r], S[mt][3][r]));
        mx = fmaxf(mx, __shfl_xor(mx, 1));
        mx = fmaxf(mx, __shfl_xor(mx, 2));
        mx = fmaxf(mx, __shfl_xor(mx, 4));
        mx = fmaxf(mx, __shfl_xor(mx, 8));
        float e0 = __expf(S[mt][0][r]-mx), e1 = __expf(S[mt][1][r]-mx);
        float e2 = __expf(S[mt][2][r]-mx), e3 = __expf(S[mt][3][r]-mx);
        S[mt][0][r]=e0; S[mt][1][r]=e1; S[mt][2][r]=e2; S[mt][3][r]=e3;
        float l = e0+e1+e2+e3;
        l += __shfl_xor(l, 1);
        l += __shfl_xor(l, 2);
        l += __shfl_xor(l, 4);
        l += __shfl_xor(l, 8);
        linv[mt][r] = 1.f/l;
      }
    }
    #pragma unroll
    for (int mt=0;mt<4;++mt)
      #pragma unroll
      for (int nt=0;nt<4;++nt)
        #pragma unroll
        for (int r=0;r<4;++r)
          Pw[(mt*16+quad*4+r)*72 + nt*16 + col] = f2bf(S[mt][nt][r]);
    asm volatile("s_waitcnt lgkmcnt(0)" ::: "memory");
    floatx4 O[4][2];
    #pragma unroll
    for (int mt=0;mt<4;++mt){ O[mt][0]=(floatx4){0.f,0.f,0.f,0.f}; O[mt][1]=(floatx4){0.f,0.f,0.f,0.f}; }
    #pragma unroll
    for (int ks=0; ks<2; ++ks){
      bhalf8 vf[2];
      #pragma unroll
      for (int nt2=0;nt2<2;++nt2)
        vf[nt2] = *(const bhalf8*)(vw + (h*32 + nt2*16 + col)*64 + ks*32 + (quad<<3));
      #pragma unroll
      for (int mt=0;mt<4;++mt){
        bhalf8 pf = *(const bhalf8*)(Pw + (mt*16+col)*72 + ks*32 + (quad<<3));
        #pragma unroll
        for (int nt2=0;nt2<2;++nt2)
          O[mt][nt2] = __builtin_amdgcn_mfma_f32_16x16x32_bf16(pf, vf[nt2], O[mt][nt2], 0, 0, 0);
      }
    }
    #pragma unroll
    for (int mt=0;mt<4;++mt)
      #pragma unroll
      for (int nt2=0;nt2<2;++nt2)
        #pragma unroll
        for (int r=0;r<4;++r)
          Ob[(mt*16+quad*4+r)*264 + h*32 + nt2*16 + col] = f2bf(O[mt][nt2][r]*linv[mt][r]);
  }
  __syncthreads();   // all k/v reads + Ob writes complete

  // ---- proj GEMM: A = Ob (LDS), B = wpf ----
  floatx4 c[4][4];
  #pragma unroll
  for (int mt=0;mt<4;++mt)
    #pragma unroll
    for (int nt=0;nt<4;++nt) c[mt][nt] = (floatx4){0.f,0.f,0.f,0.f};
  #pragma unroll
  for (int ks=0; ks<8; ++ks){
    bhalf8 a[4];
    #pragma unroll
    for (int mt=0;mt<4;++mt)
      a[mt] = *(const bhalf8*)(Ob + (mt*16+col)*264 + ks*32 + (quad<<3));
    #pragma unroll
    for (int nt=0;nt<4;++nt){
      bhalf8 bf = *(const bhalf8*)(wpf + (size_t)(((wave*4+nt)*8 + ks)*64 + lane)*8);
      #pragma unroll
      for (int mt=0;mt<4;++mt)
        c[mt][nt] = __builtin_amdgcn_mfma_f32_16x16x32_bf16(a[mt], bf, c[mt][nt], 0, 0, 0);
    }
  }
  float bb[4];
  #pragma unroll
  for (int nt=0;nt<4;++nt) bb[nt] = bp[wave*64 + nt*16 + col];

  float* obuf = (float*)Pb;                        // [32][260] overlay, Pb is dead
  unsigned short* ztb = kvz + (size_t)win * 16384; // bf16 zt, window-linear over kg bytes
  #pragma unroll
  for (int p=0; p<2; ++p){   // STATIC unroll: keeps c[] in VGPRs (rule #20)
    __syncthreads();
    #pragma unroll
    for (int mt2=0;mt2<2;++mt2){
      int mt = p*2 + mt2;
      #pragma unroll
      for (int nt=0;nt<4;++nt)
        #pragma unroll
        for (int r=0;r<4;++r)
          obuf[(mt2*16+quad*4+r)*260 + wave*64 + nt*16 + col] = c[mt][nt][r] + bb[nt];
    }
    __syncthreads();
    {
      int tl = tid >> 3, c0 = (tid & 7)*32;
      int tok = p*32 + tl;
      const float4* s = (const float4*)(obuf + tl*260 + c0);
      const uint4* zp = (const uint4*)(z0 + ((size_t)win*64 + tok)*256 + c0);
      float zv[32];
      #pragma unroll
      for (int i=0;i<4;++i) unpack8(zp[i], zv + i*8);
      uint4* d = (uint4*)(ztb + (size_t)tok*256 + c0);
      #pragma unroll
      for (int i=0;i<4;++i){
        float4 a = s[2*i], b4 = s[2*i+1];
        float r0 = a.x  + zv[i*8+0], r1 = a.y  + zv[i*8+1];
        float r2 = a.z  + zv[i*8+2], r3 = a.w  + zv[i*8+3];
        float r4 = b4.x + zv[i*8+4], r5 = b4.y + zv[i*8+5];
        float r6 = b4.z + zv[i*8+6], r7 = b4.w + zv[i*8+7];
        uint4 u;
        u.x = pk2(r0,r1); u.y = pk2(r2,r3); u.z = pk2(r4,r5); u.w = pk2(r6,r7);
        d[i] = u;
      }
    }
  }
}

// ---------- kernel 3: LN2 + MFMA MLP + residual + NCHW transpose ----------
// zt read as bf16 window-linear from the kv region. LDS 50688 B (3 blocks/CU):
// ztn[64][264] + double-buffered hbuf[2][16][264], per-(hb,mt) fc1->fc2 phases.
// NOTE: epilogue p-loop FULLY UNROLLED — runtime index into oacc[] sent the whole
// accumulator to scratch in round 6 (VGPR 84, WRITE_SIZE 1.675 GB, 2.4x slowdown).
__global__ __launch_bounds__(256, 3) void k_mlp(
    const unsigned short* __restrict__ kvzt,
    const float* __restrict__ g2, const float* __restrict__ b2,
    const unsigned short* __restrict__ w1f, const float* __restrict__ fc1b,
    const unsigned short* __restrict__ w2f, const float* __restrict__ fc2b,
    float* __restrict__ out)
{
  __shared__ __align__(16) unsigned short smu[96*264];  // ztn[64][264] + hbuf[2][16][264]
  unsigned short* ztn = smu;
  float* ob = (float*)smu;   // epilogue overlay [32][257] f32 (32896 B < 33792 B ztn)

  const int tid  = threadIdx.x;
  const int mB   = blockIdx.x << 6;
  const int lane = tid & 63, wave = tid >> 6;
  const int col  = lane & 15, quad = lane >> 4;

  const int bb_ = mB >> 14;
  const int pp0 = mB & 16383;
  const int hrow = pp0 >> 7, w0 = pp0 & 127;
  const int winb = bb_*256 + (hrow>>3)*16 + (w0>>3);
  const int tokrow = (hrow & 7)*8;
  auto ztrow = [&](int tok)->size_t{
    return ((size_t)(winb + (tok>>3))*64 + (size_t)(tokrow + (tok&7))) * 256;
  };

  // ---- LN2 (bf16 zt in) ----
  {
    const int tok = tid >> 2, qd = tid & 3;
    const uint4* zr = (const uint4*)(kvzt + ztrow(tok) + qd*64);
    float v[64];
    #pragma unroll
    for (int j=0;j<8;++j) unpack8(zr[j], v + j*8);
    float s=0.f, q=0.f;
    #pragma unroll
    for (int j=0;j<64;++j){ s += v[j]; q += v[j]*v[j]; }
    s += __shfl_xor(s,1); q += __shfl_xor(q,1);
    s += __shfl_xor(s,2); q += __shfl_xor(q,2);
    float mean = s*(1.f/256.f);
    float rstd = rsqrtf(q*(1.f/256.f) - mean*mean + 1e-5f);
    float gv[64], bv[64];
    #pragma unroll
    for (int j4=0;j4<16;++j4){
      float4 t = ((const float4*)(g2 + qd*64))[j4];
      gv[j4*4+0]=t.x; gv[j4*4+1]=t.y; gv[j4*4+2]=t.z; gv[j4*4+3]=t.w;
      float4 u = ((const float4*)(b2 + qd*64))[j4];
      bv[j4*4+0]=u.x; bv[j4*4+1]=u.y; bv[j4*4+2]=u.z; bv[j4*4+3]=u.w;
    }
    unsigned short* zd = ztn + tok*264 + qd*64;
    #pragma unroll
    for (int j8=0;j8<8;++j8){
      float r[8];
      #pragma unroll
      for (int e=0;e<8;++e) r[e] = (v[j8*8+e]-mean)*rstd*gv[j8*8+e] + bv[j8*8+e];
      uint4 u;
      u.x=pk2(r[0],r[1]); u.y=pk2(r[2],r[3]); u.z=pk2(r[4],r[5]); u.w=pk2(r[6],r[7]);
      *(uint4*)(zd + j8*8) = u;
    }
  }
  __syncthreads();

  floatx4 oacc[4][4];
  #pragma unroll
  for (int i=0;i<4;++i)
    #pragma unroll
    for (int j=0;j<4;++j) oacc[i][j] = (floatx4){0.f,0.f,0.f,0.f};

  #pragma unroll 1
  for (int hb=0; hb<4; ++hb){
    float bv1[4];
    #pragma unroll
    for (int nt=0;nt<4;++nt) bv1[nt] = fc1b[hb*256 + wave*64 + nt*16 + col];
    #pragma unroll
    for (int mt=0; mt<4; ++mt){
      unsigned short* hb16 = smu + 64*264 + (mt & 1)*16*264;   // double-buffered [16][264]
      // fc1 (16 tokens x 256 hid of this hb)
      floatx4 hacc[4];
      #pragma unroll
      for (int nt=0;nt<4;++nt) hacc[nt] = (floatx4){0.f,0.f,0.f,0.f};
      #pragma unroll
      for (int ks=0; ks<8; ++ks){
        bhalf8 a = *(const bhalf8*)(ztn + (mt*16 + col)*264 + ks*32 + (quad<<3));
        #pragma unroll
        for (int nt=0; nt<4; ++nt){
          int gnt = hb*16 + wave*4 + nt;
          bhalf8 b = *(const bhalf8*)(w1f + (size_t)((gnt*8 + ks)*64 + lane)*8);
          hacc[nt] = __builtin_amdgcn_mfma_f32_16x16x32_bf16(a, b, hacc[nt], 0, 0, 0);
        }
      }
      #pragma unroll
      for (int nt=0; nt<4; ++nt){
        int ch = wave*64 + nt*16 + col;
        #pragma unroll
        for (int r=0;r<4;++r)
          hb16[(quad*4 + r)*264 + ch] = f2bf(gelu(hacc[nt][r] + bv1[nt]));
      }
      __syncthreads();
      // fc2 (accumulate this hb's 256-hid slice into oacc[mt])
      #pragma unroll
      for (int ks=0; ks<8; ++ks){
        bhalf8 a = *(const bhalf8*)(hb16 + col*264 + ks*32 + (quad<<3));
        #pragma unroll
        for (int ot=0; ot<4; ++ot){
          int go = wave*4 + ot;
          bhalf8 b = *(const bhalf8*)(w2f + (size_t)((go*32 + hb*8 + ks)*64 + lane)*8);
          oacc[mt][ot] = __builtin_amdgcn_mfma_f32_16x16x32_bf16(a, b, oacc[mt][ot], 0, 0, 0);
        }
      }
      // no trailing barrier: next fc1 writes the other hbuf half; the next phase's
      // barrier orders reuse of this half (readers done before overwrite 2 phases later)
    }
  }

  // ---- epilogue: bias + residual (bf16 zt) + NCHW transpose, 32 tokens per pass ----
  float bo[4];
  #pragma unroll
  for (int ot=0;ot<4;++ot) bo[ot] = fc2b[wave*64 + ot*16 + col];
  const int bgl = mB >> 14, hw0 = mB & 16383;
  #pragma unroll
  for (int p=0; p<2; ++p){   // STATIC unroll: keeps oacc[] in VGPRs (rule #20)
    __syncthreads();   // prior ztn/hbuf reads (p=0) or ob scatter reads (p=1) done
    #pragma unroll
    for (int mt2=0; mt2<2; ++mt2){
      int mt = p*2 + mt2;
      #pragma unroll
      for (int ot=0; ot<4; ++ot){
        int ch = wave*64 + ot*16 + col;
        #pragma unroll
        for (int r=0;r<4;++r){
          int tok = mt*16 + quad*4 + r;
          float zv = bflo((unsigned)kvzt[ztrow(tok) + ch]);
          ob[(mt2*16 + quad*4 + r)*257 + ch] = oacc[mt][ot][r] + bo[ot] + zv;
        }
      }
    }
    __syncthreads();
    float* obase = out + (size_t)bgl*(256*16384) + hw0 + p*32;
    #pragma unroll 1
    for (int it=0; it<32; ++it){
      int l = it*256 + tid;
      int o = l >> 5, tk = l & 31;
      obase[(size_t)o*16384 + tk] = ob[tk*257 + o];
    }
  }
}

// ---------- host ----------
extern "C" void kernel_launch(void* const* d_in, const int* in_sizes, int n_in,
                              void* d_out, int out_size, void* d_ws, size_t ws_size,
                              hipStream_t stream)
{
  (void)in_sizes; (void)n_in; (void)out_size; (void)ws_size;
  const float* LH    = (const float*)d_in[0];
  const float* HL    = (const float*)d_in[1];
  const float* HH    = (const float*)d_in[2];
  const float* Spat  = (const float*)d_in[3];
  const float* w_hllh= (const float*)d_in[4];
  const float* b_hllh= (const float*)d_in[5];
  const float* w_hh  = (const float*)d_in[6];
  const float* b_hh  = (const float*)d_in[7];
  const float* w_spat= (const float*)d_in[8];
  const float* b_spat= (const float*)d_in[9];
  const float* ln1x_g= (const float*)d_in[10];
  const float* ln1x_b= (const float*)d_in[11];
  const float* ln1y_g= (const float*)d_in[12];
  const float* ln1y_b= (const float*)d_in[13];
  const float* qkv_w = (const float*)d_in[14];
  const float* qkv_b = (const float*)d_in[15];
  const float* qkv2_w= (const float*)d_in[16];
  const float* qkv2_b= (const float*)d_in[17];
  const float* qkv3_w= (const float*)d_in[18];
  const float* qkv3_b= (const float*)d_in[19];
  const float* proj_w= (const float*)d_in[20];
  const float* proj_b= (const float*)d_in[21];
  const float* rpb   = (const float*)d_in[22];
  const float* ln2_g = (const float*)d_in[23];
  const float* ln2_b = (const float*)d_in[24];
  const float* fc1_w = (const float*)d_in[25];
  const float* fc1_b = (const float*)d_in[26];
  const float* fc2_w = (const float*)d_in[27];
  const float* fc2_b = (const float*)d_in[28];
  float* out = (float*)d_out;

  char* ws = (char*)d_ws;
  size_t off = 0;
  auto alloc = [&](size_t bytes)->void*{
    void* p = ws + off; off += (bytes + 255) & ~(size_t)255; return p;
  };
  const size_t M = 131072;
  unsigned short* z0  = (unsigned short*)alloc(M*256*2);   // window-major bf16
  unsigned short* qg  = (unsigned short*)alloc(M*256*2);
  char* kv_region     = (char*)alloc(M*256*4);   // kg | vtg ; kg bytes reused as bf16 zt
  unsigned short* kg  = (unsigned short*)kv_region;
  unsigned short* vtg = (unsigned short*)(kv_region + M*256*2);
  unsigned short* ztb = (unsigned short*)kv_region;   // bf16 zt, window-linear
  unsigned short* wxf = (unsigned short*)alloc(256*128*2);
  unsigned short* wzf = (unsigned short*)alloc(256*64*2);
  unsigned short* wyf = (unsigned short*)alloc(256*64*2);
  unsigned short* wqf = (unsigned short*)alloc(256*256*2);
  unsigned short* wkf = (unsigned short*)alloc(256*256*2);
  unsigned short* wvf = (unsigned short*)alloc(256*256*2);
  unsigned short* wpf = (unsigned short*)alloc(256*256*2);
  unsigned short* w1f = (unsigned short*)alloc(1024*256*2);
  unsigned short* w2f = (unsigned short*)alloc(256*1024*2);
  float* biasf = (float*)alloc(32768*4);
  float* bqs = (float*)alloc(256*4);

  const float sc = 0.17677669529663687f;  // 1/sqrt(hd=32), folded into q weights+bias
  k_fragw<<<dim3(128),  dim3(256), 0, stream>>>(w_hllh, wxf, 256*128, 128, 1.f);
  k_fragw<<<dim3(64),   dim3(256), 0, stream>>>(w_hh,   wzf, 256*64,  64,  1.f);
  k_fragw<<<dim3(64),   dim3(256), 0, stream>>>(w_spat, wyf, 256*64,  64,  1.f);
  k_fragw<<<dim3(256),  dim3(256), 0, stream>>>(qkv_w,  wqf, 256*256, 256, sc);
  k_fragw<<<dim3(256),  dim3(256), 0, stream>>>(qkv2_w, wkf, 256*256, 256, 1.f);
  k_fragw<<<dim3(256),  dim3(256), 0, stream>>>(qkv3_w, wvf, 256*256, 256, 1.f);
  k_fragw<<<dim3(256),  dim3(256), 0, stream>>>(proj_w, wpf, 256*256, 256, 1.f);
  k_fragw<<<dim3(1024), dim3(256), 0, stream>>>(fc1_w,  w1f, 1024*256, 256, 1.f);
  k_fragw<<<dim3(1024), dim3(256), 0, stream>>>(fc2_w,  w2f, 256*1024, 1024, 1.f);
  k_bias <<<dim3(128),  dim3(256), 0, stream>>>(rpb, biasf);
  k_scale_vec<<<dim3(1), dim3(256), 0, stream>>>(qkv_b, bqs, 256, sc);

  k_front<<<dim3(2048), dim3(256), 0, stream>>>(LH, HL, HH, Spat,
      wxf, b_hllh, wzf, b_hh, wyf, b_spat,
      ln1x_g, ln1x_b, ln1y_g, ln1y_b,
      wqf, bqs, wkf, qkv2_b, wvf, qkv3_b,
      z0, qg, kg, vtg);
  k_attnproj<<<dim3(2048), dim3(256), 0, stream>>>(qg, kg, vtg, biasf, wpf, proj_b, z0, ztb);
  k_mlp<<<dim3(2048), dim3(256), 0, stream>>>(ztb, ln2_g, ln2_b,
      w1f, fc1_b, w2f, fc2_b, out);
}

// Round 10
// 810.350 us; speedup vs baseline: 1.8943x; 1.7426x over previous
//
#include <hip/hip_runtime.h>
#include <math.h>

#define DI static __device__ __forceinline__

typedef __attribute__((ext_vector_type(8))) short bhalf8;
typedef __attribute__((ext_vector_type(4))) float floatx4;

// ---------- bf16 helpers ----------
DI unsigned short f2bf(float f){
  union { float f; unsigned u; } v; v.f = f;
  unsigned r = (v.u + 0x7fffu + ((v.u >> 16) & 1u)) >> 16;
  return (unsigned short)r;
}
DI float bflo(unsigned v){ return __uint_as_float(v << 16); }
DI float bfhi(unsigned v){ return __uint_as_float(v & 0xffff0000u); }
DI unsigned pk2(float a, float b){ return (unsigned)f2bf(a) | ((unsigned)f2bf(b) << 16); }
DI void unpack8(uint4 u, float* a){
  a[0]=bflo(u.x); a[1]=bfhi(u.x); a[2]=bflo(u.y); a[3]=bfhi(u.y);
  a[4]=bflo(u.z); a[5]=bfhi(u.z); a[6]=bflo(u.w); a[7]=bfhi(u.w);
}
DI float fc(float4 v, int j){ return j==0 ? v.x : (j==1 ? v.y : (j==2 ? v.z : v.w)); }
// tanh-form GELU: max |err| vs exact ~3e-4
DI float gelu(float x){
  float u = x*(0.7978845608f + 0.0356774081f*x*x);
  float e = __expf(2.f*u);
  return x - x/(e + 1.f);
}

// ---------- prep kernels ----------
__global__ void k_scale_vec(const float* __restrict__ src, float* __restrict__ dst, int n, float s){
  int i = blockIdx.x*256 + threadIdx.x;
  if (i < n) dst[i] = src[i]*s;
}
// pack weight (O x K f32 row-major) into bf16 MFMA B-fragment order
__global__ void k_fragw(const float* __restrict__ src, unsigned short* __restrict__ dst,
                        int n, int K, float scale){
  int t = blockIdx.x*256 + threadIdx.x;
  if (t >= n) return;
  int j = t & 7, lane = (t >> 3) & 63, rest = t >> 9;
  int KS = K >> 5;
  int ks = rest % KS, nt = rest / KS;
  int row = nt*16 + (lane & 15);
  int col = ks*32 + ((lane >> 4) << 3) + j;
  dst[t] = f2bf(src[(size_t)row*K + col] * scale);
}
// relative-position bias in C-fragment layout: biasf[((h*4+mt)*4+nt)*256 + lane*4 + r]
__global__ void k_bias(const float* __restrict__ rpb, float* __restrict__ biasf){
  int t = blockIdx.x*256 + threadIdx.x;   // 32768 total
  int r = t & 3, lane = (t>>2) & 63, nt = (t>>8) & 3, mt = (t>>10) & 3, h = t>>12;
  int qtok = mt*16 + (lane>>4)*4 + r;
  int ktok = nt*16 + (lane & 15);
  int idx = ((qtok>>3) - (ktok>>3) + 7)*15 + ((qtok&7) - (ktok&7) + 7);
  biasf[t] = rpb[idx*8 + h];
}

// ---------- kernel 1: MFMA convs + LN1 + QKV MFMA GEMMs (unchanged) ----------
__global__ __launch_bounds__(256) void k_front(
    const float* __restrict__ LH, const float* __restrict__ HL,
    const float* __restrict__ HH, const float* __restrict__ Sp,
    const unsigned short* __restrict__ wxf, const float* __restrict__ bx,
    const unsigned short* __restrict__ wzf, const float* __restrict__ bz,
    const unsigned short* __restrict__ wyf, const float* __restrict__ by,
    const float* __restrict__ g1x, const float* __restrict__ b1x,
    const float* __restrict__ g1y, const float* __restrict__ b1y,
    const unsigned short* __restrict__ wqf, const float* __restrict__ bq,
    const unsigned short* __restrict__ wkf, const float* __restrict__ bk,
    const unsigned short* __restrict__ wvf, const float* __restrict__ bv,
    unsigned short* __restrict__ z0, unsigned short* __restrict__ qg,
    unsigned short* __restrict__ kg, unsigned short* __restrict__ vtg)
{
  __shared__ __align__(16) unsigned short astg[64*72];    // 9216B conv-A staging (one 64ch plane)
  __shared__ __align__(16) unsigned short sbufA[64*288];  // xn [64][264] / staging / vt [256][72]
  __shared__ __align__(16) unsigned short sbufB[64*264];  // yn [64][264]
  // LN scratch lives in sbufA tail bytes [33792, 36352): rows only use up to 16887 ushorts
  float* part  = (float*)(sbufA + 16896);   // [256][2]
  float* stats = part + 512;                // [64][2]

  const int tid = threadIdx.x;
  const int lane = tid & 63, wave = tid >> 6, col = lane & 15, quad = lane >> 4;
  const int mB = blockIdx.x << 6;
  const int b  = mB >> 14;
  const int p0 = mB & 16383;
  const int hrow = p0 >> 7, w0 = p0 & 127;
  const int winb = b*256 + (hrow>>3)*16 + (w0>>3);
  const int tokrow = (hrow & 7)*8;
  const size_t pbase = (size_t)b * (64*16384) + p0;

  float4 f0, f1, f2, f3;
  auto stage_load = [&](const float* plane){
    const float* src = plane + (size_t)((tid>>4)*4)*16384 + (tid&15)*4;
    f0 = *(const float4*)(src);
    f1 = *(const float4*)(src + 16384);
    f2 = *(const float4*)(src + 32768);
    f3 = *(const float4*)(src + 49152);
  };
  auto stage_store = [&](){
    const int tq = tid & 15, c4 = (tid >> 4) * 4;
    #pragma unroll
    for (int j=0;j<4;++j){
      int tok = tq*4 + j;
      int kk = c4 ^ (((tok>>1)&7)<<3);
      uint2 u;
      u.x = pk2(fc(f0,j), fc(f1,j));
      u.y = pk2(fc(f2,j), fc(f3,j));
      *(uint2*)(astg + tok*72 + kk) = u;
    }
  };

  floatx4 c[4][4];
  auto zeroc = [&](){
    #pragma unroll
    for (int mt=0;mt<4;++mt)
      #pragma unroll
      for (int nt=0;nt<4;++nt) c[mt][nt] = (floatx4){0.f,0.f,0.f,0.f};
  };
  auto conv_step = [&](const unsigned short* wf, int KS, int ksg0){
    #pragma unroll
    for (int ksl=0; ksl<2; ++ksl){
      bhalf8 a[4];
      #pragma unroll
      for (int mt=0;mt<4;++mt){
        int tok = mt*16 + col;
        int kk = (ksl*32 + (quad<<3)) ^ (((tok>>1)&7)<<3);
        a[mt] = *(const bhalf8*)(astg + tok*72 + kk);
      }
      #pragma unroll
      for (int nt=0;nt<4;++nt){
        bhalf8 bfr = *(const bhalf8*)(wf + (size_t)(((wave*4+nt)*KS + ksg0 + ksl)*64 + lane)*8);
        #pragma unroll
        for (int mt=0;mt<4;++mt)
          c[mt][nt] = __builtin_amdgcn_mfma_f32_16x16x32_bf16(a[mt], bfr, c[mt][nt], 0, 0, 0);
      }
    }
  };
  auto ln_frag = [&](const float* bias, const float* g, const float* bb2, unsigned short* dst){
    float bv[4];
    #pragma unroll
    for (int nt=0;nt<4;++nt) bv[nt] = bias[wave*64 + nt*16 + col];
    #pragma unroll
    for (int mt=0;mt<4;++mt){
      #pragma unroll
      for (int r=0;r<4;++r){
        float s=0.f, q=0.f;
        #pragma unroll
        for (int nt=0;nt<4;++nt){
          float v = c[mt][nt][r] + bv[nt];
          c[mt][nt][r] = v; s += v; q += v*v;
        }
        s += __shfl_xor(s,1); q += __shfl_xor(q,1);
        s += __shfl_xor(s,2); q += __shfl_xor(q,2);
        s += __shfl_xor(s,4); q += __shfl_xor(q,4);
        s += __shfl_xor(s,8); q += __shfl_xor(q,8);
        if (col == 0){
          int tok = mt*16 + quad*4 + r;
          part[(wave*64+tok)*2+0] = s;
          part[(wave*64+tok)*2+1] = q;
        }
      }
    }
    __syncthreads();
    if (tid < 64){
      float s=0.f, q=0.f;
      #pragma unroll
      for (int w2=0;w2<4;++w2){ s += part[(w2*64+tid)*2]; q += part[(w2*64+tid)*2+1]; }
      float mean = s*(1.f/256.f);
      float var  = q*(1.f/256.f) - mean*mean;
      stats[tid*2]   = mean;
      stats[tid*2+1] = rsqrtf(var + 1e-5f);
    }
    __syncthreads();
    float gv[4], av[4];
    #pragma unroll
    for (int nt=0;nt<4;++nt){ int ch = wave*64+nt*16+col; gv[nt] = g[ch]; av[nt] = bb2[ch]; }
    #pragma unroll
    for (int mt=0;mt<4;++mt)
      #pragma unroll
      for (int r=0;r<4;++r){
        int tok = mt*16 + quad*4 + r;
        float mean = stats[tok*2], rstd = stats[tok*2+1];
        #pragma unroll
        for (int nt=0;nt<4;++nt)
          dst[tok*264 + wave*64 + nt*16 + col] = f2bf((c[mt][nt][r]-mean)*rstd*gv[nt] + av[nt]);
      }
    __syncthreads();
  };

  auto gemm = [&](const unsigned short* Abuf, const unsigned short* wf, const float* bias){
    #pragma unroll
    for (int mt=0;mt<4;++mt)
      #pragma unroll
      for (int nt=0;nt<4;++nt) c[mt][nt] = (floatx4){0.f,0.f,0.f,0.f};
    #pragma unroll
    for (int ks=0; ks<8; ++ks){
      bhalf8 a[4];
      #pragma unroll
      for (int mt=0;mt<4;++mt)
        a[mt] = *(const bhalf8*)(Abuf + (mt*16+col)*264 + ks*32 + (quad<<3));
      #pragma unroll
      for (int nt=0;nt<4;++nt){
        bhalf8 bf = *(const bhalf8*)(wf + (size_t)(((wave*4+nt)*8 + ks)*64 + lane)*8);
        #pragma unroll
        for (int mt=0;mt<4;++mt)
          c[mt][nt] = __builtin_amdgcn_mfma_f32_16x16x32_bf16(a[mt], bf, c[mt][nt], 0, 0, 0);
      }
    }
    #pragma unroll
    for (int nt=0;nt<4;++nt){
      float bb2 = bias[wave*64 + nt*16 + col];
      #pragma unroll
      for (int mt=0;mt<4;++mt)
        #pragma unroll
        for (int r=0;r<4;++r) c[mt][nt][r] += bb2;
    }
  };
  auto stage_write = [&](unsigned short* gout){
    __syncthreads();   // prior readers of sbufA / astg done
    #pragma unroll
    for (int mt=0;mt<4;++mt)
      #pragma unroll
      for (int nt=0;nt<4;++nt)
        #pragma unroll
        for (int r=0;r<4;++r)
          sbufA[(mt*16+quad*4+r)*264 + wave*64 + nt*16 + col] = f2bf(c[mt][nt][r]);
    __syncthreads();
    int tok = tid >> 2, c0 = (tid & 3)*64;
    const uint4* s = (const uint4*)(sbufA + tok*264 + c0);
    uint4* d = (uint4*)(gout + ((size_t)(winb + (tok>>3)))*16384
                             + (size_t)(tokrow + (tok&7))*256 + c0);
    #pragma unroll
    for (int i=0;i<8;++i) d[i] = s[i];
  };

  // ---- z0 conv (HH, K=64) ----
  stage_load(HH + pbase);
  stage_store();
  __syncthreads();
  stage_load(LH + pbase);           // in flight over conv-z
  zeroc(); conv_step(wzf, 2, 0);
  {
    #pragma unroll
    for (int nt=0;nt<4;++nt){
      float bzv = bz[wave*64 + nt*16 + col];
      #pragma unroll
      for (int mt=0;mt<4;++mt)
        #pragma unroll
        for (int r=0;r<4;++r) c[mt][nt][r] += bzv;
    }
  }
  stage_write(z0);                  // z0 window-major
  stage_store();                    // LH -> astg (conv-z reads synced inside stage_write)
  __syncthreads();
  // ---- x conv (LH||HL, K=128) ----
  stage_load(HL + pbase);           // in flight over conv-x ks 0,1
  zeroc(); conv_step(wxf, 4, 0);
  __syncthreads();
  stage_store();                    // HL -> astg
  __syncthreads();
  stage_load(Sp + pbase);           // in flight over conv-x ks 2,3 + LN-x
  conv_step(wxf, 4, 2);
  __syncthreads();                  // astg reads done
  stage_store();                    // Sp -> astg (overlaps LN-x)
  ln_frag(bx, g1x, b1x, sbufA);     // xn
  // ---- y conv (Spat, K=64) ----
  zeroc(); conv_step(wyf, 2, 0);
  ln_frag(by, g1y, b1y, sbufB);     // yn
  // ---- QKV MFMA GEMMs ----
  gemm(sbufA, wqf, bq);
  stage_write(qg);
  gemm(sbufB, wkf, bk);
  stage_write(kg);
  gemm(sbufB, wvf, bv);
  // vt: transposed staging [256 ch][72] then per-window uint4 writes
  __syncthreads();
  #pragma unroll
  for (int mt=0;mt<4;++mt)
    #pragma unroll
    for (int nt=0;nt<4;++nt){
      int ch = wave*64 + nt*16 + col;
      uint2 u; u.x = pk2(c[mt][nt][0], c[mt][nt][1]); u.y = pk2(c[mt][nt][2], c[mt][nt][3]);
      *(uint2*)(sbufA + ch*72 + mt*16 + quad*4) = u;
    }
  __syncthreads();
  {
    int ch = tid;
    #pragma unroll
    for (int wi=0; wi<8; ++wi){
      uint4 val = *(const uint4*)(sbufA + ch*72 + wi*8);
      *(uint4*)(vtg + ((size_t)(winb + wi))*16384 + ch*64 + tokrow) = val;
    }
  }
}

// ---------- kernel 2: MFMA window attention + proj GEMM + z0 residual (fused) ----------
// zt is BF16, window-linear, written over the dead kg bytes of this same window
// (race-free: all k reads of this window precede the post-attention barrier).
// NOTE: epilogue p-loop is FULLY UNROLLED — a runtime index into c[] would force the
// whole accumulator array to scratch (rule #20; cost measured ~1 GB HBM in round 6).
__global__ __launch_bounds__(256, 2) void k_attnproj(
    const unsigned short* __restrict__ qg, const unsigned short* kg,
    const unsigned short* vtg, const float* __restrict__ biasf,
    const unsigned short* __restrict__ wpf, const float* __restrict__ bp,
    const unsigned short* __restrict__ z0, unsigned short* kvz)
{
  __shared__ __align__(16) unsigned short Pb[4*64*72];
  __shared__ __align__(16) unsigned short Ob[64*264];
  const int tid = threadIdx.x, lane = tid & 63, wave = tid >> 6;
  const int col = lane & 15, quad = lane >> 4;
  const int win = blockIdx.x;
  const size_t wbase = (size_t)win * 16384;
  const unsigned short* qw = qg + wbase;
  const unsigned short* kw = kg + wbase;
  const unsigned short* vw = vtg + wbase;
  unsigned short* Pw = Pb + wave*64*72;

  #pragma unroll 1
  for (int hh=0; hh<2; ++hh){
    const int h = wave*2 + hh;
    bhalf8 qf[4], kf[4];
    #pragma unroll
    for (int mt=0;mt<4;++mt)
      qf[mt] = *(const bhalf8*)(qw + (mt*16+col)*256 + h*32 + (quad<<3));
    #pragma unroll
    for (int nt=0;nt<4;++nt)
      kf[nt] = *(const bhalf8*)(kw + (nt*16+col)*256 + h*32 + (quad<<3));
    floatx4 S[4][4];
    #pragma unroll
    for (int mt=0;mt<4;++mt)
      #pragma unroll
      for (int nt=0;nt<4;++nt) S[mt][nt] = (floatx4){0.f,0.f,0.f,0.f};
    #pragma unroll
    for (int mt=0;mt<4;++mt)
      #pragma unroll
      for (int nt=0;nt<4;++nt)
        S[mt][nt] = __builtin_amdgcn_mfma_f32_16x16x32_bf16(qf[mt], kf[nt], S[mt][nt], 0, 0, 0);
    #pragma unroll
    for (int mt=0;mt<4;++mt)
      #pragma unroll
      for (int nt=0;nt<4;++nt){
        float4 bb = *(const float4*)(biasf + (size_t)(((h*4+mt)*4+nt))*256 + lane*4);
        S[mt][nt][0] += bb.x; S[mt][nt][1] += bb.y; S[mt][nt][2] += bb.z; S[mt][nt][3] += bb.w;
      }
    float linv[4][4];
    #pragma unroll
    for (int mt=0;mt<4;++mt){
      #pragma unroll
      for (int r=0;r<4;++r){
        float mx = fmaxf(fmaxf(S[mt][0][r], S[mt][1][r]), fmaxf(S[mt][2][r], S[mt][3][r]));
        mx = fmaxf(mx, __shfl_xor(mx, 1));
        mx = fmaxf(mx, __shfl_xor(mx, 2));
        mx = fmaxf(mx, __shfl_xor(mx, 4));
        mx = fmaxf(mx, __shfl_xor(mx, 8));
        float e0 = __expf(S[mt][0][r]-mx), e1 = __expf(S[mt][1][r]-mx);
        float e2 = __expf(S[mt][2][r]-mx), e3 = __expf(S[mt][3][r]-mx);
        S[mt][0][r]=e0; S[mt][1][r]=e1; S[mt][2][r]=e2; S[mt][3][r]=e3;
        float l = e0+e1+e2+e3;
        l += __shfl_xor(l, 1);
        l += __shfl_xor(l, 2);
        l += __shfl_xor(l, 4);
        l += __shfl_xor(l, 8);
        linv[mt][r] = 1.f/l;
      }
    }
    #pragma unroll
    for (int mt=0;mt<4;++mt)
      #pragma unroll
      for (int nt=0;nt<4;++nt)
        #pragma unroll
        for (int r=0;r<4;++r)
          Pw[(mt*16+quad*4+r)*72 + nt*16 + col] = f2bf(S[mt][nt][r]);
    asm volatile("s_waitcnt lgkmcnt(0)" ::: "memory");
    floatx4 O[4][2];
    #pragma unroll
    for (int mt=0;mt<4;++mt){ O[mt][0]=(floatx4){0.f,0.f,0.f,0.f}; O[mt][1]=(floatx4){0.f,0.f,0.f,0.f}; }
    #pragma unroll
    for (int ks=0; ks<2; ++ks){
      bhalf8 vf[2];
      #pragma unroll
      for (int nt2=0;nt2<2;++nt2)
        vf[nt2] = *(const bhalf8*)(vw + (h*32 + nt2*16 + col)*64 + ks*32 + (quad<<3));
      #pragma unroll
      for (int mt=0;mt<4;++mt){
        bhalf8 pf = *(const bhalf8*)(Pw + (mt*16+col)*72 + ks*32 + (quad<<3));
        #pragma unroll
        for (int nt2=0;nt2<2;++nt2)
          O[mt][nt2] = __builtin_amdgcn_mfma_f32_16x16x32_bf16(pf, vf[nt2], O[mt][nt2], 0, 0, 0);
      }
    }
    #pragma unroll
    for (int mt=0;mt<4;++mt)
      #pragma unroll
      for (int nt2=0;nt2<2;++nt2)
        #pragma unroll
        for (int r=0;r<4;++r)
          Ob[(mt*16+quad*4+r)*264 + h*32 + nt2*16 + col] = f2bf(O[mt][nt2][r]*linv[mt][r]);
  }
  __syncthreads();   // all k/v reads + Ob writes complete

  // ---- proj GEMM: A = Ob (LDS), B = wpf ----
  floatx4 c[4][4];
  #pragma unroll
  for (int mt=0;mt<4;++mt)
    #pragma unroll
    for (int nt=0;nt<4;++nt) c[mt][nt] = (floatx4){0.f,0.f,0.f,0.f};
  #pragma unroll
  for (int ks=0; ks<8; ++ks){
    bhalf8 a[4];
    #pragma unroll
    for (int mt=0;mt<4;++mt)
      a[mt] = *(const bhalf8*)(Ob + (mt*16+col)*264 + ks*32 + (quad<<3));
    #pragma unroll
    for (int nt=0;nt<4;++nt){
      bhalf8 bf = *(const bhalf8*)(wpf + (size_t)(((wave*4+nt)*8 + ks)*64 + lane)*8);
      #pragma unroll
      for (int mt=0;mt<4;++mt)
        c[mt][nt] = __builtin_amdgcn_mfma_f32_16x16x32_bf16(a[mt], bf, c[mt][nt], 0, 0, 0);
    }
  }
  float bb[4];
  #pragma unroll
  for (int nt=0;nt<4;++nt) bb[nt] = bp[wave*64 + nt*16 + col];

  float* obuf = (float*)Pb;                        // [32][260] overlay, Pb is dead
  unsigned short* ztb = kvz + (size_t)win * 16384; // bf16 zt, window-linear over kg bytes
  #pragma unroll
  for (int p=0; p<2; ++p){   // STATIC unroll: keeps c[] in VGPRs (rule #20)
    __syncthreads();
    #pragma unroll
    for (int mt2=0;mt2<2;++mt2){
      int mt = p*2 + mt2;
      #pragma unroll
      for (int nt=0;nt<4;++nt)
        #pragma unroll
        for (int r=0;r<4;++r)
          obuf[(mt2*16+quad*4+r)*260 + wave*64 + nt*16 + col] = c[mt][nt][r] + bb[nt];
    }
    __syncthreads();
    {
      int tl = tid >> 3, c0 = (tid & 7)*32;
      int tok = p*32 + tl;
      const float4* s = (const float4*)(obuf + tl*260 + c0);
      const uint4* zp = (const uint4*)(z0 + ((size_t)win*64 + tok)*256 + c0);
      float zv[32];
      #pragma unroll
      for (int i=0;i<4;++i) unpack8(zp[i], zv + i*8);
      uint4* d = (uint4*)(ztb + (size_t)tok*256 + c0);
      #pragma unroll
      for (int i=0;i<4;++i){
        float4 a = s[2*i], b4 = s[2*i+1];
        float r0 = a.x  + zv[i*8+0], r1 = a.y  + zv[i*8+1];
        float r2 = a.z  + zv[i*8+2], r3 = a.w  + zv[i*8+3];
        float r4 = b4.x + zv[i*8+4], r5 = b4.y + zv[i*8+5];
        float r6 = b4.z + zv[i*8+6], r7 = b4.w + zv[i*8+7];
        uint4 u;
        u.x = pk2(r0,r1); u.y = pk2(r2,r3); u.z = pk2(r4,r5); u.w = pk2(r6,r7);
        d[i] = u;
      }
    }
  }
}

// ---------- kernel 3: LN2 + MFMA MLP + residual + NCHW transpose ----------
// Round-4 coarse structure (proven 391us even WITH spills) with both spill sources
// removed: (a) launch_bounds (256,2) -> VGPR cap 256 (the (256,3) cap of ~170 forced
// LN2's live set to spill wholesale: VGPR 84, WRITE 1.1-1.7 GB in rounds 6/8);
// (b) LN2 streams g2/b2 (live set ~90 regs); (c) fc2 mt-loop statically unrolled so
// oacc[mt][ot] never sees a runtime index (rule #20 — round 4's 780MB WRITE).
// fc1 mt-loop stays unroll-1: hacc is iteration-local/static; mt only feeds addresses.
__global__ __launch_bounds__(256, 2) void k_mlp(
    const unsigned short* __restrict__ kvzt,
    const float* __restrict__ g2, const float* __restrict__ b2,
    const unsigned short* __restrict__ w1f, const float* __restrict__ fc1b,
    const unsigned short* __restrict__ w2f, const float* __restrict__ fc2b,
    float* __restrict__ out)
{
  __shared__ __align__(16) unsigned short smu[2*64*264];  // ztn[64][264] + hbuf[64][264]
  unsigned short* ztn  = smu;
  unsigned short* hbuf = smu + 64*264;
  float* ob = (float*)smu;   // epilogue overlay [64][257] f32 (65792 B <= 67584 B)

  const int tid  = threadIdx.x;
  const int mB   = blockIdx.x << 6;
  const int lane = tid & 63, wave = tid >> 6;
  const int col  = lane & 15, quad = lane >> 4;

  const int bb_ = mB >> 14;
  const int pp0 = mB & 16383;
  const int hrow = pp0 >> 7, w0 = pp0 & 127;
  const int winb = bb_*256 + (hrow>>3)*16 + (w0>>3);
  const int tokrow = (hrow & 7)*8;
  auto ztrow = [&](int tok)->size_t{
    return ((size_t)(winb + (tok>>3))*64 + (size_t)(tokrow + (tok&7))) * 256;
  };

  // ---- LN2 (bf16 zt in; g2/b2 STREAMED to keep live set ~90 regs) ----
  {
    const int tok = tid >> 2, qd = tid & 3;
    const uint4* zr = (const uint4*)(kvzt + ztrow(tok) + qd*64);
    float v[64];
    #pragma unroll
    for (int j=0;j<8;++j) unpack8(zr[j], v + j*8);
    float s=0.f, q=0.f;
    #pragma unroll
    for (int j=0;j<64;++j){ s += v[j]; q += v[j]*v[j]; }
    s += __shfl_xor(s,1); q += __shfl_xor(q,1);
    s += __shfl_xor(s,2); q += __shfl_xor(q,2);
    float mean = s*(1.f/256.f);
    float rstd = rsqrtf(q*(1.f/256.f) - mean*mean + 1e-5f);
    unsigned short* zd = ztn + tok*264 + qd*64;
    const float4* gp = (const float4*)(g2 + qd*64);
    const float4* bp = (const float4*)(b2 + qd*64);
    #pragma unroll
    for (int j8=0;j8<8;++j8){
      float4 g0 = gp[j8*2], g1 = gp[j8*2+1];
      float4 u0 = bp[j8*2], u1 = bp[j8*2+1];
      float r0 = (v[j8*8+0]-mean)*rstd*g0.x + u0.x;
      float r1 = (v[j8*8+1]-mean)*rstd*g0.y + u0.y;
      float r2 = (v[j8*8+2]-mean)*rstd*g0.z + u0.z;
      float r3 = (v[j8*8+3]-mean)*rstd*g0.w + u0.w;
      float r4 = (v[j8*8+4]-mean)*rstd*g1.x + u1.x;
      float r5 = (v[j8*8+5]-mean)*rstd*g1.y + u1.y;
      float r6 = (v[j8*8+6]-mean)*rstd*g1.z + u1.z;
      float r7 = (v[j8*8+7]-mean)*rstd*g1.w + u1.w;
      uint4 u;
      u.x=pk2(r0,r1); u.y=pk2(r2,r3); u.z=pk2(r4,r5); u.w=pk2(r6,r7);
      *(uint4*)(zd + j8*8) = u;
    }
  }
  __syncthreads();

  floatx4 oacc[4][4];
  #pragma unroll
  for (int i=0;i<4;++i)
    #pragma unroll
    for (int j=0;j<4;++j) oacc[i][j] = (floatx4){0.f,0.f,0.f,0.f};

  #pragma unroll 1
  for (int hb=0; hb<4; ++hb){
    float bv1[4];
    #pragma unroll
    for (int nt=0;nt<4;++nt) bv1[nt] = fc1b[hb*256 + wave*64 + nt*16 + col];
    // fc1: all 64 tokens x this hb's 256 hid -> hbuf (mt only feeds addresses; safe at unroll 1)
    #pragma unroll 1
    for (int mt=0; mt<4; ++mt){
      floatx4 hacc[4];
      #pragma unroll
      for (int nt=0;nt<4;++nt) hacc[nt] = (floatx4){0.f,0.f,0.f,0.f};
      #pragma unroll
      for (int ks=0; ks<8; ++ks){
        bhalf8 a = *(const bhalf8*)(ztn + (mt*16 + col)*264 + ks*32 + (quad<<3));
        #pragma unroll
        for (int nt=0; nt<4; ++nt){
          int gnt = hb*16 + wave*4 + nt;
          bhalf8 b = *(const bhalf8*)(w1f + (size_t)((gnt*8 + ks)*64 + lane)*8);
          hacc[nt] = __builtin_amdgcn_mfma_f32_16x16x32_bf16(a, b, hacc[nt], 0, 0, 0);
        }
      }
      #pragma unroll
      for (int nt=0; nt<4; ++nt){
        int ch = wave*64 + nt*16 + col;
        #pragma unroll
        for (int r=0;r<4;++r)
          hbuf[(mt*16 + quad*4 + r)*264 + ch] = f2bf(gelu(hacc[nt][r] + bv1[nt]));
      }
    }
    __syncthreads();
    // fc2: STATIC mt (oacc[mt][ot] must be compile-time-indexed — rule #20)
    #pragma unroll
    for (int mt=0; mt<4; ++mt){
      #pragma unroll
      for (int ks=0; ks<8; ++ks){
        bhalf8 a = *(const bhalf8*)(hbuf + (mt*16 + col)*264 + ks*32 + (quad<<3));
        #pragma unroll
        for (int ot=0; ot<4; ++ot){
          int go = wave*4 + ot;
          bhalf8 b = *(const bhalf8*)(w2f + (size_t)((go*32 + hb*8 + ks)*64 + lane)*8);
          oacc[mt][ot] = __builtin_amdgcn_mfma_f32_16x16x32_bf16(a, b, oacc[mt][ot], 0, 0, 0);
        }
      }
    }
    __syncthreads();
  }

  // ---- epilogue: bias + residual (bf16 zt) + NCHW transpose (all-static indices) ----
  #pragma unroll
  for (int ot=0; ot<4; ++ot){
    int o = wave*64 + ot*16 + col;
    float bo = fc2b[o];
    #pragma unroll
    for (int mt=0; mt<4; ++mt){
      #pragma unroll
      for (int r=0;r<4;++r){
        int tok = mt*16 + quad*4 + r;
        float zv = bflo((unsigned)kvzt[ztrow(tok) + o]);
        ob[tok*257 + o] = oacc[mt][ot][r] + bo + zv;
      }
    }
  }
  __syncthreads();
  {
    const int b = mB >> 14, hw0 = mB & 16383;
    float* obase = out + (size_t)b*(256*16384) + hw0;
    #pragma unroll 1
    for (int it=0; it<64; ++it){
      int l = it*256 + tid;
      int o = l >> 6, tk = l & 63;
      obase[(size_t)o*16384 + tk] = ob[tk*257 + o];
    }
  }
}

// ---------- host ----------
extern "C" void kernel_launch(void* const* d_in, const int* in_sizes, int n_in,
                              void* d_out, int out_size, void* d_ws, size_t ws_size,
                              hipStream_t stream)
{
  (void)in_sizes; (void)n_in; (void)out_size; (void)ws_size;
  const float* LH    = (const float*)d_in[0];
  const float* HL    = (const float*)d_in[1];
  const float* HH    = (const float*)d_in[2];
  const float* Spat  = (const float*)d_in[3];
  const float* w_hllh= (const float*)d_in[4];
  const float* b_hllh= (const float*)d_in[5];
  const float* w_hh  = (const float*)d_in[6];
  const float* b_hh  = (const float*)d_in[7];
  const float* w_spat= (const float*)d_in[8];
  const float* b_spat= (const float*)d_in[9];
  const float* ln1x_g= (const float*)d_in[10];
  const float* ln1x_b= (const float*)d_in[11];
  const float* ln1y_g= (const float*)d_in[12];
  const float* ln1y_b= (const float*)d_in[13];
  const float* qkv_w = (const float*)d_in[14];
  const float* qkv_b = (const float*)d_in[15];
  const float* qkv2_w= (const float*)d_in[16];
  const float* qkv2_b= (const float*)d_in[17];
  const float* qkv3_w= (const float*)d_in[18];
  const float* qkv3_b= (const float*)d_in[19];
  const float* proj_w= (const float*)d_in[20];
  const float* proj_b= (const float*)d_in[21];
  const float* rpb   = (const float*)d_in[22];
  const float* ln2_g = (const float*)d_in[23];
  const float* ln2_b = (const float*)d_in[24];
  const float* fc1_w = (const float*)d_in[25];
  const float* fc1_b = (const float*)d_in[26];
  const float* fc2_w = (const float*)d_in[27];
  const float* fc2_b = (const float*)d_in[28];
  float* out = (float*)d_out;

  char* ws = (char*)d_ws;
  size_t off = 0;
  auto alloc = [&](size_t bytes)->void*{
    void* p = ws + off; off += (bytes + 255) & ~(size_t)255; return p;
  };
  const size_t M = 131072;
  unsigned short* z0  = (unsigned short*)alloc(M*256*2);   // window-major bf16
  unsigned short* qg  = (unsigned short*)alloc(M*256*2);
  char* kv_region     = (char*)alloc(M*256*4);   // kg | vtg ; kg bytes reused as bf16 zt
  unsigned short* kg  = (unsigned short*)kv_region;
  unsigned short* vtg = (unsigned short*)(kv_region + M*256*2);
  unsigned short* ztb = (unsigned short*)kv_region;   // bf16 zt, window-linear
  unsigned short* wxf = (unsigned short*)alloc(256*128*2);
  unsigned short* wzf = (unsigned short*)alloc(256*64*2);
  unsigned short* wyf = (unsigned short*)alloc(256*64*2);
  unsigned short* wqf = (unsigned short*)alloc(256*256*2);
  unsigned short* wkf = (unsigned short*)alloc(256*256*2);
  unsigned short* wvf = (unsigned short*)alloc(256*256*2);
  unsigned short* wpf = (unsigned short*)alloc(256*256*2);
  unsigned short* w1f = (unsigned short*)alloc(1024*256*2);
  unsigned short* w2f = (unsigned short*)alloc(256*1024*2);
  float* biasf = (float*)alloc(32768*4);
  float* bqs = (float*)alloc(256*4);

  const float sc = 0.17677669529663687f;  // 1/sqrt(hd=32), folded into q weights+bias
  k_fragw<<<dim3(128),  dim3(256), 0, stream>>>(w_hllh, wxf, 256*128, 128, 1.f);
  k_fragw<<<dim3(64),   dim3(256), 0, stream>>>(w_hh,   wzf, 256*64,  64,  1.f);
  k_fragw<<<dim3(64),   dim3(256), 0, stream>>>(w_spat, wyf, 256*64,  64,  1.f);
  k_fragw<<<dim3(256),  dim3(256), 0, stream>>>(qkv_w,  wqf, 256*256, 256, sc);
  k_fragw<<<dim3(256),  dim3(256), 0, stream>>>(qkv2_w, wkf, 256*256, 256, 1.f);
  k_fragw<<<dim3(256),  dim3(256), 0, stream>>>(qkv3_w, wvf, 256*256, 256, 1.f);
  k_fragw<<<dim3(256),  dim3(256), 0, stream>>>(proj_w, wpf, 256*256, 256, 1.f);
  k_fragw<<<dim3(1024), dim3(256), 0, stream>>>(fc1_w,  w1f, 1024*256, 256, 1.f);
  k_fragw<<<dim3(1024), dim3(256), 0, stream>>>(fc2_w,  w2f, 256*1024, 1024, 1.f);
  k_bias <<<dim3(128),  dim3(256), 0, stream>>>(rpb, biasf);
  k_scale_vec<<<dim3(1), dim3(256), 0, stream>>>(qkv_b, bqs, 256, sc);

  k_front<<<dim3(2048), dim3(256), 0, stream>>>(LH, HL, HH, Spat,
      wxf, b_hllh, wzf, b_hh, wyf, b_spat,
      ln1x_g, ln1x_b, ln1y_g, ln1y_b,
      wqf, bqs, wkf, qkv2_b, wvf, qkv3_b,
      z0, qg, kg, vtg);
  k_attnproj<<<dim3(2048), dim3(256), 0, stream>>>(qg, kg, vtg, biasf, wpf, proj_b, z0, ztb);
  k_mlp<<<dim3(2048), dim3(256), 0, stream>>>(ztb, ln2_g, ln2_b,
      w1f, fc1_b, w2f, fc2_b, out);
}